// Round 11
// baseline (549.536 us; speedup 1.0000x reference)
//
#include <hip/hip_runtime.h>
#include <math.h>

// B=8, N=1024, C=1024, H=16, hd=64, n_tasks=10, n_frq=3000
#define NFRQ 3000

typedef __bf16 bf16;
typedef __attribute__((ext_vector_type(8))) __bf16 bf16x8;
typedef __attribute__((ext_vector_type(4))) __bf16 bf16x4;
typedef __attribute__((ext_vector_type(4))) float floatx4;

__device__ __forceinline__ floatx4 mfma16(bf16x8 a, bf16x8 b, floatx4 c) {
  return __builtin_amdgcn_mfma_f32_16x16x32_bf16(a, b, c, 0, 0, 0);
}

// async global->LDS, 16B per lane, dest = base + lane*16.
// NOTE (R10 post-mortem): nonzero imm offset arg produced NaN-corruption;
// keep offset=0 and do address math on the pointer.
__device__ __forceinline__ void async_load16(const bf16* g, bf16* l) {
  __builtin_amdgcn_global_load_lds(
      (const __attribute__((address_space(1))) unsigned int*)g,
      (__attribute__((address_space(3))) unsigned int*)l, 16, 0, 0);
}

__device__ __forceinline__ float fexp2(float x) {
  return __builtin_amdgcn_exp2f(x);
}

// ---------------------------------------------------------------------------
// Merged prep: DCT basis + 4 fp32->bf16 conversions in ONE launch.
__global__ __launch_bounds__(256) void prep_kernel(
    const float* __restrict__ W_qkv, const float* __restrict__ W_proj,
    const float* __restrict__ x, const float* __restrict__ Sf,
    bf16* __restrict__ Bmtb, bf16* __restrict__ Wcbq,
    bf16* __restrict__ Wprojb, bf16* __restrict__ xb,
    bf16* __restrict__ S2b) {
  int r = blockIdx.x;
  if (r < 1024) {
    // DCT-II transposed bf16: out[t]=Bm[i][j] with j=t>>10,i=t&1023 (4/thread)
    int base = r * 1024 + (int)threadIdx.x * 4;
    const float cst = 0.04419417382415922f;  // sqrt(2)/32
    const float w = 1.5339807878856412e-3f;  // pi/2048
    bf16x4 o;
#pragma unroll
    for (int u = 0; u < 4; ++u) {
      int t = base + u;
      int j = t >> 10, i = t & 1023;
      int K = (i * (2 * j + 1)) & 4095;
      float v = (i == 0) ? 0.03125f : cst * __cosf((float)K * w);
      o[u] = (__bf16)v;
    }
    *(bf16x4*)&Bmtb[base] = o;
    return;
  }
  const float* src;
  bf16* dst;
  float scale = 1.0f;
  int i;
  if (r < 2048) {
    i = (r - 1024) * 256 + threadIdx.x;
    src = W_qkv; dst = Wcbq;
    scale = 0.18033688011112042f;  // 0.125 * log2(e)
  } else if (r < 3072) {
    i = (r - 2048) * 256 + threadIdx.x;
    src = W_proj; dst = Wprojb;
  } else if (r < 11264) {
    i = (r - 3072) * 256 + threadIdx.x;
    src = x; dst = xb;
  } else {
    i = (r - 11264) * 256 + threadIdx.x;
    src = Sf; dst = S2b;
  }
  float4 f = ((const float4*)src)[i];
  bf16x4 o = {(__bf16)(f.x * scale), (__bf16)(f.y * scale),
              (__bf16)(f.z * scale), (__bf16)(f.w * scale)};
  *(bf16x4*)&dst[(size_t)i * 4] = o;
}

// ---------------------------------------------------------------------------
// Dense scatter: S[id] += coef (2 fp32 planes, k and v). One thread per nz.
__global__ __launch_bounds__(256) void scatter_s(const float* __restrict__ coef_k,
                                                 const float* __restrict__ coef_v,
                                                 const int* __restrict__ idx,
                                                 const int* __restrict__ task,
                                                 float* __restrict__ S) {
  int nz = blockIdx.x * 256 + threadIdx.x;
  if (nz >= 10 * NFRQ || nz >= (*task + 1) * NFRQ) return;
  int id = idx[nz];
  atomicAdd(S + id, coef_k[nz]);
  atomicAdd(S + (1u << 20) + id, coef_v[nz]);
}

// ---------------------------------------------------------------------------
// R10: 256x256 qkv GEMM, R6's proven 2-barrier counted-vmcnt loop, with
// BK 64->32 so LDS = 64KB -> 2 BLOCKS/CU.
// History: R6 (BK=64, 128KB LDS, 1 block/CU) = 77.5us; R7's 4-phase split
// REGRESSED to 102.9us (per-phase read->MFMA dependency stalls + 5
// barriers/tile with no co-resident work to hide them -> falsified).
// R6's own numbers expose the real limiter: per-block ~51.6us, 384 blocks
// at 1/CU -> makespan = 1.5x per-block = 77.4us (exact match measured).
// The last 128 blocks run with half the machine idle -- a TAIL problem.
// Fix: BK=32 halves the tile slice -> As/Bs = [2][256][32] x2 = 64KB ->
// 2 blocks/CU: 384 blocks on 512 slots = ONE scheduling round (no tail),
// and the co-resident block's compute hides this block's vmcnt/barrier
// drains (the mechanism that made the old 128^2 kernel latency-tolerant).
// Bank arithmetic at 64B row stride: bank(row,chunk) = (row&1)*16+chunk*4;
// the wave's quad->chunk mapping spreads 64 lanes uniformly over all 32
// banks (8 accesses/bank = b128 structural floor) -> NO swizzle needed,
// read chunk = quad*8. Staging: each inst = 16 rows x 64B aligned segments
// (fully coalesced, 4 lanes/64B line -- same sector efficiency as R6).
// vmcnt ledger: 4 insts/wave/tile, 1-tile-deep prefetch -> steady
// vmcnt(4) (tile kt's 4 retired, kt+1's 4 in flight); last tile vmcnt(0).
// K-sequence per acc element: tile kt, chunk quad -> k = kt*32 + quad*8,
// ascending == R6's exact order -> outputs BIT-IDENTICAL (absmax must
// stay exactly 0.0546875; tolerance is marginal per R3).
__global__ __launch_bounds__(512, 4) void gemm256_qkv(const bf16* __restrict__ A,
                                                      const bf16* __restrict__ B,
                                                      bf16* __restrict__ Cb,
                                                      bf16* __restrict__ vt) {
  __shared__ bf16 As[2][256][32];   // 32KB (double buffer, row-major LD=32)
  __shared__ bf16 Bs[2][256][32];   // 32KB
  int t = threadIdx.x, w = t >> 6, lane = t & 63;
  int q15 = lane & 15, quad = lane >> 4;
  // XCD swizzle (bijective; gridDim.y = 32, band = 4)
  int lid = blockIdx.x + gridDim.x * blockIdx.y;
  int band = gridDim.y >> 3;
  int xcd = lid & 7, tt = lid >> 3;
  int by = xcd * band + tt % band;
  int bx = tt / band;
  int m0 = by * 256, n0 = bx * 256;
  int wm = (w >> 2) * 128, wn = (w & 3) * 64;

  floatx4 acc[8][4];
#pragma unroll
  for (int i = 0; i < 8; ++i)
#pragma unroll
    for (int j = 0; j < 4; ++j) acc[i][j] = (floatx4){0.f, 0.f, 0.f, 0.f};

  // Staging geometry: inst covers 16 rows x 64B. Lane l -> sub-row l>>2,
  // chunk l&3 (linear LDS dest == [row][32] row-major, no swizzle).
  int r16 = lane >> 2, ch4 = lane & 3;
  const bf16* Agl = A + (size_t)(m0 + r16) * 1024 + ch4 * 8;
  const bf16* Bgl = B + (size_t)(n0 + r16) * 1024 + ch4 * 8;

  // prologue: stage K-tile 0 into buffer 0 (4 insts/wave: 2 A + 2 B)
#pragma unroll
  for (int s = 0; s < 2; ++s) {
    int rb = w * 32 + s * 16;
    async_load16(Agl + (size_t)rb * 1024, &As[0][rb][0]);
    async_load16(Bgl + (size_t)rb * 1024, &Bs[0][rb][0]);
  }

  for (int kt = 0; kt < 32; ++kt) {
    int cur = kt & 1;
    if (kt + 1 < 32) {
      int k0 = (kt + 1) * 32;
#pragma unroll
      for (int s = 0; s < 2; ++s) {
        int rb = w * 32 + s * 16;
        async_load16(Agl + (size_t)rb * 1024 + k0, &As[cur ^ 1][rb][0]);
        async_load16(Bgl + (size_t)rb * 1024 + k0, &Bs[cur ^ 1][rb][0]);
      }
      // wait for tile kt's 4 loads (tile kt+1's 4 newest stay in flight)
      asm volatile("s_waitcnt vmcnt(4)\n\ts_barrier" ::: "memory");
    } else {
      asm volatile("s_waitcnt vmcnt(0)\n\ts_barrier" ::: "memory");
    }
    // compute tile kt from buf[cur]: frag row wm/wn + i*16 + q15, chunk=quad
    bf16x8 af[8], bfr[4];
#pragma unroll
    for (int i = 0; i < 8; ++i)
      af[i] = *(const bf16x8*)&As[cur][wm + i * 16 + q15][quad * 8];
#pragma unroll
    for (int j = 0; j < 4; ++j)
      bfr[j] = *(const bf16x8*)&Bs[cur][wn + j * 16 + q15][quad * 8];
#pragma unroll
    for (int i = 0; i < 8; ++i)
#pragma unroll
      for (int j = 0; j < 4; ++j)
        acc[i][j] = mfma16(af[i], bfr[j], acc[i][j]);
    // all waves done READING buf[cur] before iteration kt+1 overwrites it.
    asm volatile("s_waitcnt lgkmcnt(0)\n\ts_barrier" ::: "memory");
  }

  if (n0 >= 2048) {
    // v band: transposed store, acc[i][j][0..3] = 4 consecutive rows (mi)
#pragma unroll
    for (int i = 0; i < 8; ++i) {
      int gm = m0 + wm + i * 16 + quad * 4;
      int p = gm >> 10, mi = gm & 1023;
#pragma unroll
      for (int j = 0; j < 4; ++j) {
        int vchan = (n0 + wn - 2048) + j * 16 + q15;
        bf16x4 pk = {(__bf16)acc[i][j][0], (__bf16)acc[i][j][1],
                     (__bf16)acc[i][j][2], (__bf16)acc[i][j][3]};
        *(bf16x4*)&vt[((((size_t)p << 10) | vchan) << 10) | mi] = pk;
      }
    }
    return;
  }

#pragma unroll
  for (int i = 0; i < 8; ++i)
#pragma unroll
    for (int r = 0; r < 4; ++r) {
      int gm = m0 + wm + i * 16 + quad * 4 + r;
      size_t rowo = (size_t)gm * 3072 + n0 + wn;
#pragma unroll
      for (int j = 0; j < 4; ++j) {
        int col = j * 16 + q15;
        Cb[rowo + col] = (__bf16)acc[i][j][r];
      }
    }
}

// ---------------------------------------------------------------------------
// MFMA NT GEMM, 64x64 block tile — for SMALL GEMMs (lora1, lora2, proj).
__global__ __launch_bounds__(256) void gemm64_bf16_nt(const bf16* __restrict__ A,
                                                      const bf16* __restrict__ B,
                                                      bf16* __restrict__ Cb,
                                                      float* __restrict__ Cf,
                                                      const float* __restrict__ addend,
                                                      const float* __restrict__ bias,
                                                      bf16* __restrict__ vt,
                                                      int vt_col0,
                                                      int N) {
  __shared__ bf16 As[2][4][64][8];   // 8KB (double buffer)
  __shared__ bf16 Bs[2][4][64][8];   // 8KB
  size_t zoff = (size_t)blockIdx.z << 20;
  B += zoff;
  if (Cb) Cb += zoff;
  if (addend) addend += zoff;
  int t = threadIdx.x, w = t >> 6, lane = t & 63;
  int q15 = lane & 15, quad = lane >> 4;
  // XCD swizzle (bijective; gridDim.y % 8 == 0 for all our grids)
  int lid = blockIdx.x + gridDim.x * blockIdx.y;
  int band = gridDim.y >> 3;
  int xcd = lid & 7, tt = lid >> 3;
  int by = xcd * band + tt % band;
  int bx = tt / band;
  int m0 = by * 64, n0 = bx * 64;
  int wm = (w >> 1) * 32, wn = (w & 1) * 32;
  floatx4 acc[2][2];
#pragma unroll
  for (int i = 0; i < 2; ++i)
#pragma unroll
    for (int j = 0; j < 2; ++j) acc[i][j] = (floatx4){0.f, 0.f, 0.f, 0.f};

  const bf16* Ag = A + (size_t)(m0 + lane) * 1024 + w * 8;
  const bf16* Bg = B + (size_t)(n0 + lane) * 1024 + w * 8;

  // prologue: stage K-step 0 into buffer 0 (wave w stages kchunk w, 64 rows)
  async_load16(Ag, &As[0][w][0][0]);
  async_load16(Bg, &Bs[0][w][0][0]);

  for (int it = 0; it < 32; ++it) {
    int cur = it & 1;
    __syncthreads();   // drains loads(it)
    if (it + 1 < 32) {
      int k0 = (it + 1) * 32;
      async_load16(Ag + k0, &As[cur ^ 1][w][0][0]);
      async_load16(Bg + k0, &Bs[cur ^ 1][w][0][0]);
    }
    bf16x8 af[2], bfr[2];
#pragma unroll
    for (int i = 0; i < 2; ++i)
      af[i] = *(const bf16x8*)&As[cur][quad][wm + i * 16 + q15][0];
#pragma unroll
    for (int j = 0; j < 2; ++j)
      bfr[j] = *(const bf16x8*)&Bs[cur][quad][wn + j * 16 + q15][0];
#pragma unroll
    for (int i = 0; i < 2; ++i)
#pragma unroll
      for (int j = 0; j < 2; ++j) acc[i][j] = mfma16(af[i], bfr[j], acc[i][j]);
  }

  if (vt && (n0 + wn) >= vt_col0) {
#pragma unroll
    for (int i = 0; i < 2; ++i) {
      int gm = m0 + wm + i * 16 + quad * 4;          // row (4 consecutive)
      int p = gm >> 10, mi = gm & 1023;
#pragma unroll
      for (int j = 0; j < 2; ++j) {
        int vchan = (n0 + wn - vt_col0) + j * 16 + q15;
        bf16x4 pk = {(__bf16)acc[i][j][0], (__bf16)acc[i][j][1],
                     (__bf16)acc[i][j][2], (__bf16)acc[i][j][3]};
        *(bf16x4*)&vt[((((size_t)p << 10) | vchan) << 10) | mi] = pk;
      }
    }
    return;
  }

#pragma unroll
  for (int i = 0; i < 2; ++i)
#pragma unroll
    for (int r = 0; r < 4; ++r) {
      int gm = m0 + wm + i * 16 + quad * 4 + r;
      size_t rowo = (size_t)gm * N + n0 + wn;
#pragma unroll
      for (int j = 0; j < 2; ++j) {
        int col = j * 16 + q15;
        float v = acc[i][j][r];
        if (Cf) {
          Cf[rowo + col] = v + (bias ? bias[n0 + wn + col] : 0.f);
        } else {
          if (addend) v += addend[rowo + col];
          Cb[rowo + col] = (__bf16)v;
        }
      }
    }
}

// ---------------------------------------------------------------------------
// Flash attention, S^T formulation (R9 structure). Block = (b,h,128 q rows),
// 4 waves. Q fragments in registers; PsB aliases dead Qs; K/V double-buffered
// with cross-barrier prefetch, one barrier per kv-tile. No online softmax
// (logits pre-scaled by 0.125*log2e, bounded). XCD swizzle keeps a (b,h)'s
// q-tiles on one XCD.
__global__ __launch_bounds__(256) void attn_mfma(const bf16* __restrict__ qkvb,
                                                 const bf16* __restrict__ Vt,
                                                 bf16* __restrict__ attn_out) {
  __shared__ __align__(16) char smem[49152];
  bf16 (*Qs)[128][8] = (bf16(*)[128][8])smem;              // [8][128][8] 16KB
  bf16* PsB = (bf16*)smem;                                 // aliases Qs after prologue
  bf16 (*Ks)[8][64][8] = (bf16(*)[8][64][8])(smem + 16384); // [2][8][64][8] 16KB
  bf16 (*Vs)[8][64][8] = (bf16(*)[8][64][8])(smem + 32768); // [2][8][64][8] 16KB

  int t = threadIdx.x, w = t >> 6, lane = t & 63;
  int q15 = lane & 15, quad = lane >> 4;
  int lid = blockIdx.x + (blockIdx.y << 3);
  int xcd = lid & 7, rr = lid >> 3;
  int q0 = (rr & 7) * 128;
  int bh = xcd + ((rr >> 3) << 3);
  int b = bh >> 4, h = bh & 15;

  const bf16* Qg = qkvb + (size_t)(b * 1024 + q0) * 3072 + h * 64;
  const bf16* Kg = qkvb + (size_t)(b * 1024) * 3072 + 1024 + h * 64;
  const bf16* Vg = Vt + (size_t)(bh * 64) * 1024;

  // prologue: stage Q tile + K/V tile 0 (buffer 0)
#pragma unroll
  for (int cc = 0; cc < 2; ++cc) {
    int kc = w * 2 + cc;
    async_load16(Qg + (size_t)lane * 3072 + kc * 8,        &Qs[kc][0][0]);
    async_load16(Qg + (size_t)(64 + lane) * 3072 + kc * 8, &Qs[kc][64][0]);
  }
  {
    const bf16* Kg2 = Kg + (size_t)lane * 3072;
    const bf16* Vg2 = Vg + (size_t)lane * 1024;
    async_load16(Kg2 + (w * 2) * 8,     &Ks[0][w * 2][0][0]);
    async_load16(Kg2 + (w * 2 + 1) * 8, &Ks[0][w * 2 + 1][0][0]);
    async_load16(Vg2 + (w * 2) * 8,     &Vs[0][w * 2][0][0]);
    async_load16(Vg2 + (w * 2 + 1) * 8, &Vs[0][w * 2 + 1][0][0]);
  }
  __syncthreads();

  // hoist Q fragments (invariant over kv loop)
  bf16x8 qfr[2][2];
#pragma unroll
  for (int ks = 0; ks < 2; ++ks)
#pragma unroll
    for (int nt = 0; nt < 2; ++nt)
      qfr[ks][nt] = *(const bf16x8*)&Qs[ks * 4 + quad][w * 32 + nt * 16 + q15][0];

  floatx4 oacc[4][2];
  float l_i[2] = {0.f, 0.f};
#pragma unroll
  for (int nt = 0; nt < 2; ++nt)
#pragma unroll
    for (int mt = 0; mt < 4; ++mt) oacc[mt][nt] = (floatx4){0.f, 0.f, 0.f, 0.f};

  for (int kt = 0; kt < 16; ++kt) {
    int cur = kt & 1;
    __syncthreads();   // drains prefetch(kt); at kt=0 also fences Qs->PsB reuse
    if (kt + 1 < 16) {
      int kv0n = (kt + 1) * 64;
      const bf16* Kg3 = Kg + (size_t)(kv0n + lane) * 3072;
      const bf16* Vg3 = Vg + (size_t)lane * 1024 + kv0n;
      async_load16(Kg3 + (w * 2) * 8,     &Ks[cur ^ 1][w * 2][0][0]);
      async_load16(Kg3 + (w * 2 + 1) * 8, &Ks[cur ^ 1][w * 2 + 1][0][0]);
      async_load16(Vg3 + (w * 2) * 8,     &Vs[cur ^ 1][w * 2][0][0]);
      async_load16(Vg3 + (w * 2 + 1) * 8, &Vs[cur ^ 1][w * 2 + 1][0][0]);
    }

    // S^T = K Q^T
    floatx4 sacc[4][2];
#pragma unroll
    for (int mt = 0; mt < 4; ++mt)
#pragma unroll
      for (int nt = 0; nt < 2; ++nt) sacc[mt][nt] = (floatx4){0.f, 0.f, 0.f, 0.f};
#pragma unroll
    for (int ks = 0; ks < 2; ++ks) {
      bf16x8 kf[4];
#pragma unroll
      for (int mt = 0; mt < 4; ++mt)
        kf[mt] = *(const bf16x8*)&Ks[cur][ks * 4 + quad][mt * 16 + q15][0];
#pragma unroll
      for (int mt = 0; mt < 4; ++mt)
#pragma unroll
        for (int nt = 0; nt < 2; ++nt)
          sacc[mt][nt] = mfma16(kf[mt], qfr[ks][nt], sacc[mt][nt]);
    }

    // softmax numerator: p = exp2(s) (no max/rescale; logits bounded)
#pragma unroll
    for (int nt = 0; nt < 2; ++nt) {
      float rsum = 0.f;
#pragma unroll
      for (int mt = 0; mt < 4; ++mt)
#pragma unroll
        for (int r = 0; r < 4; ++r) {
          float p = fexp2(sacc[mt][nt][r]);
          sacc[mt][nt][r] = p;
          rsum += p;
        }
      rsum += __shfl_xor(rsum, 16);
      rsum += __shfl_xor(rsum, 32);
      l_i[nt] += rsum;
    }

    // P^T -> per-wave LDS region (B-frag layout), same-wave RAW via lgkmcnt
#pragma unroll
    for (int nt = 0; nt < 2; ++nt)
#pragma unroll
      for (int mt = 0; mt < 4; ++mt) {
        bf16x4 pk = {(__bf16)sacc[mt][nt][0], (__bf16)sacc[mt][nt][1],
                     (__bf16)sacc[mt][nt][2], (__bf16)sacc[mt][nt][3]};
        int kc = mt * 2 + (quad >> 1);
        *(bf16x4*)&PsB[(size_t)(w * 2 + nt) * 1024 + kc * 128 + q15 * 8 + (quad & 1) * 4] = pk;
      }

    // O^T += V^T P^T
#pragma unroll
    for (int ks = 0; ks < 2; ++ks) {
      bf16x8 vf[4], pf[2];
#pragma unroll
      for (int mt = 0; mt < 4; ++mt)
        vf[mt] = *(const bf16x8*)&Vs[cur][ks * 4 + quad][mt * 16 + q15][0];
#pragma unroll
      for (int nt = 0; nt < 2; ++nt)
        pf[nt] = *(const bf16x8*)&PsB[(size_t)(w * 2 + nt) * 1024 + (ks * 4 + quad) * 128 + q15 * 8];
#pragma unroll
      for (int mt = 0; mt < 4; ++mt)
#pragma unroll
        for (int nt = 0; nt < 2; ++nt) oacc[mt][nt] = mfma16(vf[mt], pf[nt], oacc[mt][nt]);
    }
  }

  __syncthreads();
  bf16* T = (bf16*)smem + w * 2304;   // [32 q][72]; overlaps dead Qs/PsB + Ks head
#pragma unroll
  for (int nt = 0; nt < 2; ++nt) {
    float inv = 1.f / l_i[nt];
#pragma unroll
    for (int mt = 0; mt < 4; ++mt) {
      bf16x4 pk = {(__bf16)(oacc[mt][nt][0] * inv), (__bf16)(oacc[mt][nt][1] * inv),
                   (__bf16)(oacc[mt][nt][2] * inv), (__bf16)(oacc[mt][nt][3] * inv)};
      *(bf16x4*)&T[(nt * 16 + q15) * 72 + mt * 16 + quad * 4] = pk;
    }
  }
  __syncthreads();
  int row = lane >> 1, ch = (lane & 1) * 32;
  const bf16* Tr = T + row * 72 + ch;
  bf16* outp = attn_out + (size_t)(b * 1024 + q0 + w * 32 + row) * 1024 + h * 64 + ch;
#pragma unroll
  for (int i = 0; i < 4; ++i) *(bf16x8*)&outp[i * 8] = *(const bf16x8*)&Tr[i * 8];
}

// ---------------------------------------------------------------------------
extern "C" void kernel_launch(void* const* d_in, const int* in_sizes, int n_in,
                              void* d_out, int out_size, void* d_ws, size_t ws_size,
                              hipStream_t stream) {
  (void)in_sizes; (void)n_in; (void)out_size; (void)ws_size;
  const float* x       = (const float*)d_in[0];   // 8x1024x1024
  const float* W_qkv   = (const float*)d_in[1];   // 3072x1024
  const float* W_proj  = (const float*)d_in[2];   // 1024x1024
  const float* b_proj  = (const float*)d_in[3];   // 1024
  const float* coef_k  = (const float*)d_in[4];   // 10x3000
  const float* coef_v  = (const float*)d_in[5];   // 10x3000
  const int*   indices = (const int*)d_in[6];     // 10x3000
  const int*   task    = (const int*)d_in[7];     // scalar

  // Workspace (106 MB peak). attn_out aliases the dead Sf/S2b/Tt region.
  char* w8 = (char*)d_ws;
  float* Sf     = (float*)(w8);                   // 8MB  (2 fp32 planes, transient)
  bf16*  S2b    = (bf16*) (w8 + (8u  << 20));     // 4MB  [2048][1024] (transient)
  bf16*  Tt     = (bf16*) (w8 + (12u << 20));     // 4MB  [2][1024][1024] (transient)
  bf16*  Bmtb   = (bf16*) (w8 + (16u << 20));     // 2MB
  bf16*  Wcb    = (bf16*) (w8 + (18u << 20));     // 6MB  [3072][1024]
  bf16*  xb     = (bf16*) (w8 + (24u << 20));     // 16MB
  bf16*  qkvb   = (bf16*) (w8 + (40u << 20));     // 48MB [8192][3072]
  bf16*  Vt     = (bf16*) (w8 + (88u << 20));     // 16MB [128][64][1024]
  bf16*  Wprojb = (bf16*) (w8 + (104u << 20));    // 2MB
  bf16*  attnout= (bf16*) (w8);                   // 16MB alias (Sf/S2b/Tt dead)

  // Dense S scatter (fp32 planes), then ONE merged prep launch
  hipMemsetAsync(Sf, 0, (size_t)8 << 20, stream);
  scatter_s<<<118, 256, 0, stream>>>(coef_k, coef_v, indices, task, Sf);
  prep_kernel<<<13312, 256, 0, stream>>>(W_qkv, W_proj, x, Sf,
                                         Bmtb, Wcb, Wprojb, xb, S2b);

  // LoRA: T = S @ Bm (stored transposed per plane), then both band GEMMs
  gemm64_bf16_nt<<<dim3(16, 32), 256, 0, stream>>>(S2b, Bmtb, nullptr, nullptr,
                                                   nullptr, nullptr, Tt, 0, 1024);
  gemm64_bf16_nt<<<dim3(16, 16, 2), 256, 0, stream>>>(Bmtb, Tt, Wcb + (1u << 20), nullptr,
                                                      W_qkv + (1u << 20), nullptr, nullptr,
                                                      1 << 30, 1024);

  // qkv = xb @ Wcb^T -> q,k bands bf16 into qkvb; v band transposed into Vt.
  // R10: BK=32 / 64KB-LDS / 2-blocks-per-CU variant of R6's 2-barrier loop.
  gemm256_qkv<<<dim3(12, 32), 512, 0, stream>>>(xb, Wcb, qkvb, Vt);

  // attention
  attn_mfma<<<dim3(8, 128), 256, 0, stream>>>(qkvb, Vt, attnout);

  // out = attn_out @ W_proj^T + b_proj  (fp32 out)
  gemm64_bf16_nt<<<dim3(16, 128), 256, 0, stream>>>(attnout, Wprojb, nullptr, (float*)d_out,
                                                    nullptr, b_proj, nullptr, 1 << 30, 1024);
}

// Round 12
// 357.344 us; speedup vs baseline: 1.5378x; 1.5378x over previous
//
#include <hip/hip_runtime.h>
#include <math.h>

// B=8, N=1024, C=1024, H=16, hd=64, n_tasks=10, n_frq=3000
#define NFRQ 3000

typedef __bf16 bf16;
typedef __attribute__((ext_vector_type(8))) __bf16 bf16x8;
typedef __attribute__((ext_vector_type(4))) __bf16 bf16x4;
typedef __attribute__((ext_vector_type(4))) float floatx4;

__device__ __forceinline__ floatx4 mfma16(bf16x8 a, bf16x8 b, floatx4 c) {
  return __builtin_amdgcn_mfma_f32_16x16x32_bf16(a, b, c, 0, 0, 0);
}

// async global->LDS, 16B per lane, dest = base + lane*16.
// NOTE (R10 post-mortem): nonzero imm offset arg produced NaN-corruption;
// keep offset=0 and do address math on the pointer.
__device__ __forceinline__ void async_load16(const bf16* g, bf16* l) {
  __builtin_amdgcn_global_load_lds(
      (const __attribute__((address_space(1))) unsigned int*)g,
      (__attribute__((address_space(3))) unsigned int*)l, 16, 0, 0);
}

__device__ __forceinline__ float fexp2(float x) {
  return __builtin_amdgcn_exp2f(x);
}

// ---------------------------------------------------------------------------
// Merged prep: DCT basis + 4 fp32->bf16 conversions in ONE launch.
__global__ __launch_bounds__(256) void prep_kernel(
    const float* __restrict__ W_qkv, const float* __restrict__ W_proj,
    const float* __restrict__ x, const float* __restrict__ Sf,
    bf16* __restrict__ Bmtb, bf16* __restrict__ Wcbq,
    bf16* __restrict__ Wprojb, bf16* __restrict__ xb,
    bf16* __restrict__ S2b) {
  int r = blockIdx.x;
  if (r < 1024) {
    // DCT-II transposed bf16: out[t]=Bm[i][j] with j=t>>10,i=t&1023 (4/thread)
    int base = r * 1024 + (int)threadIdx.x * 4;
    const float cst = 0.04419417382415922f;  // sqrt(2)/32
    const float w = 1.5339807878856412e-3f;  // pi/2048
    bf16x4 o;
#pragma unroll
    for (int u = 0; u < 4; ++u) {
      int t = base + u;
      int j = t >> 10, i = t & 1023;
      int K = (i * (2 * j + 1)) & 4095;
      float v = (i == 0) ? 0.03125f : cst * __cosf((float)K * w);
      o[u] = (__bf16)v;
    }
    *(bf16x4*)&Bmtb[base] = o;
    return;
  }
  const float* src;
  bf16* dst;
  float scale = 1.0f;
  int i;
  if (r < 2048) {
    i = (r - 1024) * 256 + threadIdx.x;
    src = W_qkv; dst = Wcbq;
    scale = 0.18033688011112042f;  // 0.125 * log2(e)
  } else if (r < 3072) {
    i = (r - 2048) * 256 + threadIdx.x;
    src = W_proj; dst = Wprojb;
  } else if (r < 11264) {
    i = (r - 3072) * 256 + threadIdx.x;
    src = x; dst = xb;
  } else {
    i = (r - 11264) * 256 + threadIdx.x;
    src = Sf; dst = S2b;
  }
  float4 f = ((const float4*)src)[i];
  bf16x4 o = {(__bf16)(f.x * scale), (__bf16)(f.y * scale),
              (__bf16)(f.z * scale), (__bf16)(f.w * scale)};
  *(bf16x4*)&dst[(size_t)i * 4] = o;
}

// ---------------------------------------------------------------------------
// Dense scatter: S[id] += coef (2 fp32 planes, k and v). One thread per nz.
__global__ __launch_bounds__(256) void scatter_s(const float* __restrict__ coef_k,
                                                 const float* __restrict__ coef_v,
                                                 const int* __restrict__ idx,
                                                 const int* __restrict__ task,
                                                 float* __restrict__ S) {
  int nz = blockIdx.x * 256 + threadIdx.x;
  if (nz >= 10 * NFRQ || nz >= (*task + 1) * NFRQ) return;
  int id = idx[nz];
  atomicAdd(S + id, coef_k[nz]);
  atomicAdd(S + (1u << 20) + id, coef_v[nz]);
}

// ---------------------------------------------------------------------------
// R11: 256x256 qkv GEMM, BK=32 / 64KB LDS (2 blocks/CU), R6's 2-barrier
// counted-vmcnt loop. Fixes R10's two counter-diagnosed bugs:
//  (1) R10's __launch_bounds__(512,4) capped VGPR at 64 -> acc[8][4]
//      (128 regs) spilled to scratch: WRITE_SIZE 49->660MB, 292us.
//      Now (512,2): compiler free (~90 VGPR); hardware still reaches
//      2 blocks/CU naturally (LDS 64KB, VGPR<128 -> 16 waves/CU, m69).
//  (2) R10's linear [256][32] layout was an 8-WAY bank conflict (4.7M
//      measured): bank_start = 16*(row&1)+4*quad -- 8 same-parity rows
//      per quad share one 4-bank group. Fix: chunk XOR swizzle (rule #21
//      both-sides): k-chunk c of row r stored at LDS slot c^((r>>1)&3);
//      source lane (sr=l>>2, sc=l&3) fetches global chunk sc^((sr>>1)&3)
//      (lane-constant; stays in the row's 64B window -> coalescing kept);
//      read slot = quad^((q15>>1)&3). Each (parity,pair) combo -> distinct
//      4-bank group, 2 lanes each -> 2-way = free (m136).
// Tail theory (unfalsified by R10's bug-caused regression): R6 at
// 1 block/CU had makespan 1.5x per-block (384 blocks, 256 CUs) -- exact
// match to 77.5us. 2 blocks/CU -> one scheduling round, and co-resident
// blocks hide each other's vmcnt/barrier drains.
// K-sequence per acc element: k = kt*32 + quad*8, ascending == R6/R4's
// exact order -> outputs BIT-IDENTICAL (absmax must stay 0.0546875).
__global__ __launch_bounds__(512, 2) void gemm256_qkv(const bf16* __restrict__ A,
                                                      const bf16* __restrict__ B,
                                                      bf16* __restrict__ Cb,
                                                      bf16* __restrict__ vt) {
  __shared__ bf16 As[2][256][32];   // 32KB (double buffer, row-major LD=32)
  __shared__ bf16 Bs[2][256][32];   // 32KB
  int t = threadIdx.x, w = t >> 6, lane = t & 63;
  int q15 = lane & 15, quad = lane >> 4;
  // XCD swizzle (bijective; gridDim.y = 32, band = 4)
  int lid = blockIdx.x + gridDim.x * blockIdx.y;
  int band = gridDim.y >> 3;
  int xcd = lid & 7, tt = lid >> 3;
  int by = xcd * band + tt % band;
  int bx = tt / band;
  int m0 = by * 256, n0 = bx * 256;
  int wm = (w >> 2) * 128, wn = (w & 3) * 64;

  floatx4 acc[8][4];
#pragma unroll
  for (int i = 0; i < 8; ++i)
#pragma unroll
    for (int j = 0; j < 4; ++j) acc[i][j] = (floatx4){0.f, 0.f, 0.f, 0.f};

  // Staging geometry: inst covers 16 rows x 64B. Lane l -> sub-row sr=l>>2,
  // LDS chunk slot sc=l&3; global k-chunk = sc ^ ((sr>>1)&3) (lane-constant
  // across insts since row-block bases are multiples of 16).
  int sr = lane >> 2, sc = lane & 3;
  const bf16* Agl = A + (size_t)(m0 + sr) * 1024 + (sc ^ ((sr >> 1) & 3)) * 8;
  const bf16* Bgl = B + (size_t)(n0 + sr) * 1024 + (sc ^ ((sr >> 1) & 3)) * 8;

  // prologue: stage K-tile 0 into buffer 0 (4 insts/wave: 2 A + 2 B)
#pragma unroll
  for (int s = 0; s < 2; ++s) {
    int rb = w * 32 + s * 16;
    async_load16(Agl + (size_t)rb * 1024, &As[0][rb][0]);
    async_load16(Bgl + (size_t)rb * 1024, &Bs[0][rb][0]);
  }

  // read-side swizzle: k-chunk quad of row r lives at slot quad^((r>>1)&3);
  // all fragment rows are == q15 (mod 16), so the XOR term is q15-derived.
  int ksw = (quad ^ ((q15 >> 1) & 3)) * 8;
  for (int kt = 0; kt < 32; ++kt) {
    int cur = kt & 1;
    if (kt + 1 < 32) {
      int k0 = (kt + 1) * 32;
#pragma unroll
      for (int s = 0; s < 2; ++s) {
        int rb = w * 32 + s * 16;
        async_load16(Agl + (size_t)rb * 1024 + k0, &As[cur ^ 1][rb][0]);
        async_load16(Bgl + (size_t)rb * 1024 + k0, &Bs[cur ^ 1][rb][0]);
      }
      // wait for tile kt's 4 loads (tile kt+1's 4 newest stay in flight)
      asm volatile("s_waitcnt vmcnt(4)\n\ts_barrier" ::: "memory");
    } else {
      asm volatile("s_waitcnt vmcnt(0)\n\ts_barrier" ::: "memory");
    }
    // compute tile kt from buf[cur]: frag row wm/wn + i*16 + q15
    bf16x8 af[8], bfr[4];
#pragma unroll
    for (int i = 0; i < 8; ++i)
      af[i] = *(const bf16x8*)&As[cur][wm + i * 16 + q15][ksw];
#pragma unroll
    for (int j = 0; j < 4; ++j)
      bfr[j] = *(const bf16x8*)&Bs[cur][wn + j * 16 + q15][ksw];
#pragma unroll
    for (int i = 0; i < 8; ++i)
#pragma unroll
      for (int j = 0; j < 4; ++j)
        acc[i][j] = mfma16(af[i], bfr[j], acc[i][j]);
    // all waves done READING buf[cur] before iteration kt+1 overwrites it.
    asm volatile("s_waitcnt lgkmcnt(0)\n\ts_barrier" ::: "memory");
  }

  if (n0 >= 2048) {
    // v band: transposed store, acc[i][j][0..3] = 4 consecutive rows (mi)
#pragma unroll
    for (int i = 0; i < 8; ++i) {
      int gm = m0 + wm + i * 16 + quad * 4;
      int p = gm >> 10, mi = gm & 1023;
#pragma unroll
      for (int j = 0; j < 4; ++j) {
        int vchan = (n0 + wn - 2048) + j * 16 + q15;
        bf16x4 pk = {(__bf16)acc[i][j][0], (__bf16)acc[i][j][1],
                     (__bf16)acc[i][j][2], (__bf16)acc[i][j][3]};
        *(bf16x4*)&vt[((((size_t)p << 10) | vchan) << 10) | mi] = pk;
      }
    }
    return;
  }

#pragma unroll
  for (int i = 0; i < 8; ++i)
#pragma unroll
    for (int r = 0; r < 4; ++r) {
      int gm = m0 + wm + i * 16 + quad * 4 + r;
      size_t rowo = (size_t)gm * 3072 + n0 + wn;
#pragma unroll
      for (int j = 0; j < 4; ++j) {
        int col = j * 16 + q15;
        Cb[rowo + col] = (__bf16)acc[i][j][r];
      }
    }
}

// ---------------------------------------------------------------------------
// MFMA NT GEMM, 64x64 block tile — for SMALL GEMMs (lora1, lora2, proj).
__global__ __launch_bounds__(256) void gemm64_bf16_nt(const bf16* __restrict__ A,
                                                      const bf16* __restrict__ B,
                                                      bf16* __restrict__ Cb,
                                                      float* __restrict__ Cf,
                                                      const float* __restrict__ addend,
                                                      const float* __restrict__ bias,
                                                      bf16* __restrict__ vt,
                                                      int vt_col0,
                                                      int N) {
  __shared__ bf16 As[2][4][64][8];   // 8KB (double buffer)
  __shared__ bf16 Bs[2][4][64][8];   // 8KB
  size_t zoff = (size_t)blockIdx.z << 20;
  B += zoff;
  if (Cb) Cb += zoff;
  if (addend) addend += zoff;
  int t = threadIdx.x, w = t >> 6, lane = t & 63;
  int q15 = lane & 15, quad = lane >> 4;
  // XCD swizzle (bijective; gridDim.y % 8 == 0 for all our grids)
  int lid = blockIdx.x + gridDim.x * blockIdx.y;
  int band = gridDim.y >> 3;
  int xcd = lid & 7, tt = lid >> 3;
  int by = xcd * band + tt % band;
  int bx = tt / band;
  int m0 = by * 64, n0 = bx * 64;
  int wm = (w >> 1) * 32, wn = (w & 1) * 32;
  floatx4 acc[2][2];
#pragma unroll
  for (int i = 0; i < 2; ++i)
#pragma unroll
    for (int j = 0; j < 2; ++j) acc[i][j] = (floatx4){0.f, 0.f, 0.f, 0.f};

  const bf16* Ag = A + (size_t)(m0 + lane) * 1024 + w * 8;
  const bf16* Bg = B + (size_t)(n0 + lane) * 1024 + w * 8;

  // prologue: stage K-step 0 into buffer 0 (wave w stages kchunk w, 64 rows)
  async_load16(Ag, &As[0][w][0][0]);
  async_load16(Bg, &Bs[0][w][0][0]);

  for (int it = 0; it < 32; ++it) {
    int cur = it & 1;
    __syncthreads();   // drains loads(it)
    if (it + 1 < 32) {
      int k0 = (it + 1) * 32;
      async_load16(Ag + k0, &As[cur ^ 1][w][0][0]);
      async_load16(Bg + k0, &Bs[cur ^ 1][w][0][0]);
    }
    bf16x8 af[2], bfr[2];
#pragma unroll
    for (int i = 0; i < 2; ++i)
      af[i] = *(const bf16x8*)&As[cur][quad][wm + i * 16 + q15][0];
#pragma unroll
    for (int j = 0; j < 2; ++j)
      bfr[j] = *(const bf16x8*)&Bs[cur][quad][wn + j * 16 + q15][0];
#pragma unroll
    for (int i = 0; i < 2; ++i)
#pragma unroll
      for (int j = 0; j < 2; ++j) acc[i][j] = mfma16(af[i], bfr[j], acc[i][j]);
  }

  if (vt && (n0 + wn) >= vt_col0) {
#pragma unroll
    for (int i = 0; i < 2; ++i) {
      int gm = m0 + wm + i * 16 + quad * 4;          // row (4 consecutive)
      int p = gm >> 10, mi = gm & 1023;
#pragma unroll
      for (int j = 0; j < 2; ++j) {
        int vchan = (n0 + wn - vt_col0) + j * 16 + q15;
        bf16x4 pk = {(__bf16)acc[i][j][0], (__bf16)acc[i][j][1],
                     (__bf16)acc[i][j][2], (__bf16)acc[i][j][3]};
        *(bf16x4*)&vt[((((size_t)p << 10) | vchan) << 10) | mi] = pk;
      }
    }
    return;
  }

#pragma unroll
  for (int i = 0; i < 2; ++i)
#pragma unroll
    for (int r = 0; r < 4; ++r) {
      int gm = m0 + wm + i * 16 + quad * 4 + r;
      size_t rowo = (size_t)gm * N + n0 + wn;
#pragma unroll
      for (int j = 0; j < 2; ++j) {
        int col = j * 16 + q15;
        float v = acc[i][j][r];
        if (Cf) {
          Cf[rowo + col] = v + (bias ? bias[n0 + wn + col] : 0.f);
        } else {
          if (addend) v += addend[rowo + col];
          Cb[rowo + col] = (__bf16)v;
        }
      }
    }
}

// ---------------------------------------------------------------------------
// Flash attention, S^T formulation (R9 structure). Block = (b,h,128 q rows),
// 4 waves. Q fragments in registers; PsB aliases dead Qs; K/V double-buffered
// with cross-barrier prefetch, one barrier per kv-tile. No online softmax
// (logits pre-scaled by 0.125*log2e, bounded). XCD swizzle keeps a (b,h)'s
// q-tiles on one XCD.
__global__ __launch_bounds__(256) void attn_mfma(const bf16* __restrict__ qkvb,
                                                 const bf16* __restrict__ Vt,
                                                 bf16* __restrict__ attn_out) {
  __shared__ __align__(16) char smem[49152];
  bf16 (*Qs)[128][8] = (bf16(*)[128][8])smem;              // [8][128][8] 16KB
  bf16* PsB = (bf16*)smem;                                 // aliases Qs after prologue
  bf16 (*Ks)[8][64][8] = (bf16(*)[8][64][8])(smem + 16384); // [2][8][64][8] 16KB
  bf16 (*Vs)[8][64][8] = (bf16(*)[8][64][8])(smem + 32768); // [2][8][64][8] 16KB

  int t = threadIdx.x, w = t >> 6, lane = t & 63;
  int q15 = lane & 15, quad = lane >> 4;
  int lid = blockIdx.x + (blockIdx.y << 3);
  int xcd = lid & 7, rr = lid >> 3;
  int q0 = (rr & 7) * 128;
  int bh = xcd + ((rr >> 3) << 3);
  int b = bh >> 4, h = bh & 15;

  const bf16* Qg = qkvb + (size_t)(b * 1024 + q0) * 3072 + h * 64;
  const bf16* Kg = qkvb + (size_t)(b * 1024) * 3072 + 1024 + h * 64;
  const bf16* Vg = Vt + (size_t)(bh * 64) * 1024;

  // prologue: stage Q tile + K/V tile 0 (buffer 0)
#pragma unroll
  for (int cc = 0; cc < 2; ++cc) {
    int kc = w * 2 + cc;
    async_load16(Qg + (size_t)lane * 3072 + kc * 8,        &Qs[kc][0][0]);
    async_load16(Qg + (size_t)(64 + lane) * 3072 + kc * 8, &Qs[kc][64][0]);
  }
  {
    const bf16* Kg2 = Kg + (size_t)lane * 3072;
    const bf16* Vg2 = Vg + (size_t)lane * 1024;
    async_load16(Kg2 + (w * 2) * 8,     &Ks[0][w * 2][0][0]);
    async_load16(Kg2 + (w * 2 + 1) * 8, &Ks[0][w * 2 + 1][0][0]);
    async_load16(Vg2 + (w * 2) * 8,     &Vs[0][w * 2][0][0]);
    async_load16(Vg2 + (w * 2 + 1) * 8, &Vs[0][w * 2 + 1][0][0]);
  }
  __syncthreads();

  // hoist Q fragments (invariant over kv loop)
  bf16x8 qfr[2][2];
#pragma unroll
  for (int ks = 0; ks < 2; ++ks)
#pragma unroll
    for (int nt = 0; nt < 2; ++nt)
      qfr[ks][nt] = *(const bf16x8*)&Qs[ks * 4 + quad][w * 32 + nt * 16 + q15][0];

  floatx4 oacc[4][2];
  float l_i[2] = {0.f, 0.f};
#pragma unroll
  for (int nt = 0; nt < 2; ++nt)
#pragma unroll
    for (int mt = 0; mt < 4; ++mt) oacc[mt][nt] = (floatx4){0.f, 0.f, 0.f, 0.f};

  for (int kt = 0; kt < 16; ++kt) {
    int cur = kt & 1;
    __syncthreads();   // drains prefetch(kt); at kt=0 also fences Qs->PsB reuse
    if (kt + 1 < 16) {
      int kv0n = (kt + 1) * 64;
      const bf16* Kg3 = Kg + (size_t)(kv0n + lane) * 3072;
      const bf16* Vg3 = Vg + (size_t)lane * 1024 + kv0n;
      async_load16(Kg3 + (w * 2) * 8,     &Ks[cur ^ 1][w * 2][0][0]);
      async_load16(Kg3 + (w * 2 + 1) * 8, &Ks[cur ^ 1][w * 2 + 1][0][0]);
      async_load16(Vg3 + (w * 2) * 8,     &Vs[cur ^ 1][w * 2][0][0]);
      async_load16(Vg3 + (w * 2 + 1) * 8, &Vs[cur ^ 1][w * 2 + 1][0][0]);
    }

    // S^T = K Q^T
    floatx4 sacc[4][2];
#pragma unroll
    for (int mt = 0; mt < 4; ++mt)
#pragma unroll
      for (int nt = 0; nt < 2; ++nt) sacc[mt][nt] = (floatx4){0.f, 0.f, 0.f, 0.f};
#pragma unroll
    for (int ks = 0; ks < 2; ++ks) {
      bf16x8 kf[4];
#pragma unroll
      for (int mt = 0; mt < 4; ++mt)
        kf[mt] = *(const bf16x8*)&Ks[cur][ks * 4 + quad][mt * 16 + q15][0];
#pragma unroll
      for (int mt = 0; mt < 4; ++mt)
#pragma unroll
        for (int nt = 0; nt < 2; ++nt)
          sacc[mt][nt] = mfma16(kf[mt], qfr[ks][nt], sacc[mt][nt]);
    }

    // softmax numerator: p = exp2(s) (no max/rescale; logits bounded)
#pragma unroll
    for (int nt = 0; nt < 2; ++nt) {
      float rsum = 0.f;
#pragma unroll
      for (int mt = 0; mt < 4; ++mt)
#pragma unroll
        for (int r = 0; r < 4; ++r) {
          float p = fexp2(sacc[mt][nt][r]);
          sacc[mt][nt][r] = p;
          rsum += p;
        }
      rsum += __shfl_xor(rsum, 16);
      rsum += __shfl_xor(rsum, 32);
      l_i[nt] += rsum;
    }

    // P^T -> per-wave LDS region (B-frag layout), same-wave RAW via lgkmcnt
#pragma unroll
    for (int nt = 0; nt < 2; ++nt)
#pragma unroll
      for (int mt = 0; mt < 4; ++mt) {
        bf16x4 pk = {(__bf16)sacc[mt][nt][0], (__bf16)sacc[mt][nt][1],
                     (__bf16)sacc[mt][nt][2], (__bf16)sacc[mt][nt][3]};
        int kc = mt * 2 + (quad >> 1);
        *(bf16x4*)&PsB[(size_t)(w * 2 + nt) * 1024 + kc * 128 + q15 * 8 + (quad & 1) * 4] = pk;
      }

    // O^T += V^T P^T
#pragma unroll
    for (int ks = 0; ks < 2; ++ks) {
      bf16x8 vf[4], pf[2];
#pragma unroll
      for (int mt = 0; mt < 4; ++mt)
        vf[mt] = *(const bf16x8*)&Vs[cur][ks * 4 + quad][mt * 16 + q15][0];
#pragma unroll
      for (int nt = 0; nt < 2; ++nt)
        pf[nt] = *(const bf16x8*)&PsB[(size_t)(w * 2 + nt) * 1024 + (ks * 4 + quad) * 128 + q15 * 8];
#pragma unroll
      for (int mt = 0; mt < 4; ++mt)
#pragma unroll
        for (int nt = 0; nt < 2; ++nt) oacc[mt][nt] = mfma16(vf[mt], pf[nt], oacc[mt][nt]);
    }
  }

  __syncthreads();
  bf16* T = (bf16*)smem + w * 2304;   // [32 q][72]; overlaps dead Qs/PsB + Ks head
#pragma unroll
  for (int nt = 0; nt < 2; ++nt) {
    float inv = 1.f / l_i[nt];
#pragma unroll
    for (int mt = 0; mt < 4; ++mt) {
      bf16x4 pk = {(__bf16)(oacc[mt][nt][0] * inv), (__bf16)(oacc[mt][nt][1] * inv),
                   (__bf16)(oacc[mt][nt][2] * inv), (__bf16)(oacc[mt][nt][3] * inv)};
      *(bf16x4*)&T[(nt * 16 + q15) * 72 + mt * 16 + quad * 4] = pk;
    }
  }
  __syncthreads();
  int row = lane >> 1, ch = (lane & 1) * 32;
  const bf16* Tr = T + row * 72 + ch;
  bf16* outp = attn_out + (size_t)(b * 1024 + q0 + w * 32 + row) * 1024 + h * 64 + ch;
#pragma unroll
  for (int i = 0; i < 4; ++i) *(bf16x8*)&outp[i * 8] = *(const bf16x8*)&Tr[i * 8];
}

// ---------------------------------------------------------------------------
extern "C" void kernel_launch(void* const* d_in, const int* in_sizes, int n_in,
                              void* d_out, int out_size, void* d_ws, size_t ws_size,
                              hipStream_t stream) {
  (void)in_sizes; (void)n_in; (void)out_size; (void)ws_size;
  const float* x       = (const float*)d_in[0];   // 8x1024x1024
  const float* W_qkv   = (const float*)d_in[1];   // 3072x1024
  const float* W_proj  = (const float*)d_in[2];   // 1024x1024
  const float* b_proj  = (const float*)d_in[3];   // 1024
  const float* coef_k  = (const float*)d_in[4];   // 10x3000
  const float* coef_v  = (const float*)d_in[5];   // 10x3000
  const int*   indices = (const int*)d_in[6];     // 10x3000
  const int*   task    = (const int*)d_in[7];     // scalar

  // Workspace (106 MB peak). attn_out aliases the dead Sf/S2b/Tt region.
  char* w8 = (char*)d_ws;
  float* Sf     = (float*)(w8);                   // 8MB  (2 fp32 planes, transient)
  bf16*  S2b    = (bf16*) (w8 + (8u  << 20));     // 4MB  [2048][1024] (transient)
  bf16*  Tt     = (bf16*) (w8 + (12u << 20));     // 4MB  [2][1024][1024] (transient)
  bf16*  Bmtb   = (bf16*) (w8 + (16u << 20));     // 2MB
  bf16*  Wcb    = (bf16*) (w8 + (18u << 20));     // 6MB  [3072][1024]
  bf16*  xb     = (bf16*) (w8 + (24u << 20));     // 16MB
  bf16*  qkvb   = (bf16*) (w8 + (40u << 20));     // 48MB [8192][3072]
  bf16*  Vt     = (bf16*) (w8 + (88u << 20));     // 16MB [128][64][1024]
  bf16*  Wprojb = (bf16*) (w8 + (104u << 20));    // 2MB
  bf16*  attnout= (bf16*) (w8);                   // 16MB alias (Sf/S2b/Tt dead)

  // Dense S scatter (fp32 planes), then ONE merged prep launch
  hipMemsetAsync(Sf, 0, (size_t)8 << 20, stream);
  scatter_s<<<118, 256, 0, stream>>>(coef_k, coef_v, indices, task, Sf);
  prep_kernel<<<13312, 256, 0, stream>>>(W_qkv, W_proj, x, Sf,
                                         Bmtb, Wcb, Wprojb, xb, S2b);

  // LoRA: T = S @ Bm (stored transposed per plane), then both band GEMMs
  gemm64_bf16_nt<<<dim3(16, 32), 256, 0, stream>>>(S2b, Bmtb, nullptr, nullptr,
                                                   nullptr, nullptr, Tt, 0, 1024);
  gemm64_bf16_nt<<<dim3(16, 16, 2), 256, 0, stream>>>(Bmtb, Tt, Wcb + (1u << 20), nullptr,
                                                      W_qkv + (1u << 20), nullptr, nullptr,
                                                      1 << 30, 1024);

  // qkv = xb @ Wcb^T -> q,k bands bf16 into qkvb; v band transposed into Vt.
  // R11: BK=32 / 64KB LDS / natural 2-blocks-per-CU (launch_bounds(512,2),
  // VGPR free) + chunk-XOR swizzle fixing R10's 8-way conflict.
  gemm256_qkv<<<dim3(12, 32), 512, 0, stream>>>(xb, Wcb, qkvb, Vt);

  // attention
  attn_mfma<<<dim3(8, 128), 256, 0, stream>>>(qkvb, Vt, attnout);

  // out = attn_out @ W_proj^T + b_proj  (fp32 out)
  gemm64_bf16_nt<<<dim3(16, 128), 256, 0, stream>>>(attnout, Wprojb, nullptr, (float*)d_out,
                                                    nullptr, b_proj, nullptr, 1 << 30, 1024);
}

// Round 13
// 322.905 us; speedup vs baseline: 1.7019x; 1.1067x over previous
//
#include <hip/hip_runtime.h>
#include <math.h>

// B=8, N=1024, C=1024, H=16, hd=64, n_tasks=10, n_frq=3000
#define NFRQ 3000

typedef __bf16 bf16;
typedef __attribute__((ext_vector_type(8))) __bf16 bf16x8;
typedef __attribute__((ext_vector_type(4))) __bf16 bf16x4;
typedef __attribute__((ext_vector_type(4))) float floatx4;

__device__ __forceinline__ floatx4 mfma16(bf16x8 a, bf16x8 b, floatx4 c) {
  return __builtin_amdgcn_mfma_f32_16x16x32_bf16(a, b, c, 0, 0, 0);
}

// async global->LDS, 16B per lane, dest = base + lane*16.
__device__ __forceinline__ void async_load16(const bf16* g, bf16* l) {
  __builtin_amdgcn_global_load_lds(
      (const __attribute__((address_space(1))) unsigned int*)g,
      (__attribute__((address_space(3))) unsigned int*)l, 16, 0, 0);
}

__device__ __forceinline__ float fexp2(float x) {
  return __builtin_amdgcn_exp2f(x);
}

// ---------------------------------------------------------------------------
// Merged prep: DCT basis + 4 fp32->bf16 conversions in ONE launch.
__global__ __launch_bounds__(256) void prep_kernel(
    const float* __restrict__ W_qkv, const float* __restrict__ W_proj,
    const float* __restrict__ x, const float* __restrict__ Sf,
    bf16* __restrict__ Bmtb, bf16* __restrict__ Wcbq,
    bf16* __restrict__ Wprojb, bf16* __restrict__ xb,
    bf16* __restrict__ S2b) {
  int r = blockIdx.x;
  if (r < 1024) {
    // DCT-II transposed bf16: out[t]=Bm[i][j] with j=t>>10,i=t&1023 (4/thread)
    int base = r * 1024 + (int)threadIdx.x * 4;
    const float cst = 0.04419417382415922f;  // sqrt(2)/32
    const float w = 1.5339807878856412e-3f;  // pi/2048
    bf16x4 o;
#pragma unroll
    for (int u = 0; u < 4; ++u) {
      int t = base + u;
      int j = t >> 10, i = t & 1023;
      int K = (i * (2 * j + 1)) & 4095;
      float v = (i == 0) ? 0.03125f : cst * __cosf((float)K * w);
      o[u] = (__bf16)v;
    }
    *(bf16x4*)&Bmtb[base] = o;
    return;
  }
  const float* src;
  bf16* dst;
  float scale = 1.0f;
  int i;
  if (r < 2048) {
    i = (r - 1024) * 256 + threadIdx.x;
    src = W_qkv; dst = Wcbq;
    scale = 0.18033688011112042f;  // 0.125 * log2(e)
  } else if (r < 3072) {
    i = (r - 2048) * 256 + threadIdx.x;
    src = W_proj; dst = Wprojb;
  } else if (r < 11264) {
    i = (r - 3072) * 256 + threadIdx.x;
    src = x; dst = xb;
  } else {
    i = (r - 11264) * 256 + threadIdx.x;
    src = Sf; dst = S2b;
  }
  float4 f = ((const float4*)src)[i];
  bf16x4 o = {(__bf16)(f.x * scale), (__bf16)(f.y * scale),
              (__bf16)(f.z * scale), (__bf16)(f.w * scale)};
  *(bf16x4*)&dst[(size_t)i * 4] = o;
}

// ---------------------------------------------------------------------------
// Dense scatter: S[id] += coef (2 fp32 planes, k and v). One thread per nz.
__global__ __launch_bounds__(256) void scatter_s(const float* __restrict__ coef_k,
                                                 const float* __restrict__ coef_v,
                                                 const int* __restrict__ idx,
                                                 const int* __restrict__ task,
                                                 float* __restrict__ S) {
  int nz = blockIdx.x * 256 + threadIdx.x;
  if (nz >= 10 * NFRQ || nz >= (*task + 1) * NFRQ) return;
  int id = idx[nz];
  atomicAdd(S + id, coef_k[nz]);
  atomicAdd(S + (1u << 20) + id, coef_v[nz]);
}

// ---------------------------------------------------------------------------
// R12: qkv GEMM reverted VERBATIM to the R6 measured-best (77.5us):
// 256x256, BK=64, 128KB LDS, coalesced row-major staging + XOR swizzle
// (rule #21 both-sides), 2-barrier counted-vmcnt loop.
// Exploration record: R7 4-phase split = 102.9 (regression); R10 BK=32 +
// forced occupancy = 292 (VGPR cap spill + 8-way conflict); R11 bug-fixed
// BK=32 = 94.5 (co-resident blocks merely time-share; no overlap win).
// Conclusion: this structure's floor ~77.5us ≈ 384MB staged / ~5TB/s
// effective staging rate. Further qkv work needs a staged-bytes reduction,
// not scheduling. Outputs bit-identical across all these variants
// (absmax exactly 0.0546875 every passing run).
__global__ __launch_bounds__(512, 2) void gemm256_qkv(const bf16* __restrict__ A,
                                                      const bf16* __restrict__ B,
                                                      bf16* __restrict__ Cb,
                                                      bf16* __restrict__ vt) {
  __shared__ bf16 As[2][256][64];   // 64KB (double buffer, row-major LD=64)
  __shared__ bf16 Bs[2][256][64];   // 64KB
  int t = threadIdx.x, w = t >> 6, lane = t & 63;
  int q15 = lane & 15, quad = lane >> 4;
  // XCD swizzle (bijective; gridDim.y = 32, band = 4)
  int lid = blockIdx.x + gridDim.x * blockIdx.y;
  int band = gridDim.y >> 3;
  int xcd = lid & 7, tt = lid >> 3;
  int by = xcd * band + tt % band;
  int bx = tt / band;
  int m0 = by * 256, n0 = bx * 256;
  int wm = (w >> 2) * 128, wn = (w & 3) * 64;

  floatx4 acc[8][4];
#pragma unroll
  for (int i = 0; i < 8; ++i)
#pragma unroll
    for (int j = 0; j < 4; ++j) acc[i][j] = (floatx4){0.f, 0.f, 0.f, 0.f};

  // Staging geometry: inst s covers tile-rows [s*8, s*8+8). Lane l -> row
  // sub sr = l>>3, chunk sc = l&7; global k-offset chunk = sc ^ sr
  // (lane-constant across insts since (s*8+sr)&7 == sr).
  int sr = lane >> 3, sc = lane & 7;
  const bf16* Agl = A + (size_t)(m0 + sr) * 1024 + (sc ^ sr) * 8;
  const bf16* Bgl = B + (size_t)(n0 + sr) * 1024 + (sc ^ sr) * 8;

  // prologue: stage K-tile 0 into buffer 0 (8 insts/wave: 4 A + 4 B)
#pragma unroll
  for (int s = 0; s < 4; ++s) {
    int rb = w * 32 + s * 8;
    async_load16(Agl + (size_t)rb * 1024, &As[0][rb][0]);
    async_load16(Bgl + (size_t)rb * 1024, &Bs[0][rb][0]);
  }

  for (int kt = 0; kt < 16; ++kt) {
    int cur = kt & 1;
    if (kt + 1 < 16) {
      int k0 = (kt + 1) * 64;
#pragma unroll
      for (int s = 0; s < 4; ++s) {
        int rb = w * 32 + s * 8;
        async_load16(Agl + (size_t)rb * 1024 + k0, &As[cur ^ 1][rb][0]);
        async_load16(Bgl + (size_t)rb * 1024 + k0, &Bs[cur ^ 1][rb][0]);
      }
      // wait for tile kt's 8 loads (tile kt+1's 8 newest stay in flight)
      asm volatile("s_waitcnt vmcnt(8)\n\ts_barrier" ::: "memory");
    } else {
      asm volatile("s_waitcnt vmcnt(0)\n\ts_barrier" ::: "memory");
    }
    // compute tile kt from buf[cur]. Fragment row = wm+i*16+q15; its k-data
    // for chunk kc lives at swizzled col (kc ^ (row&7))*8, row&7 == q15&7.
    int rp = q15 & 7;
#pragma unroll
    for (int kk = 0; kk < 2; ++kk) {
      int kc = kk * 4 + quad;
      int ksw = (kc ^ rp) * 8;
      bf16x8 af[8], bfr[4];
#pragma unroll
      for (int i = 0; i < 8; ++i)
        af[i] = *(const bf16x8*)&As[cur][wm + i * 16 + q15][ksw];
#pragma unroll
      for (int j = 0; j < 4; ++j)
        bfr[j] = *(const bf16x8*)&Bs[cur][wn + j * 16 + q15][ksw];
#pragma unroll
      for (int i = 0; i < 8; ++i)
#pragma unroll
        for (int j = 0; j < 4; ++j)
          acc[i][j] = mfma16(af[i], bfr[j], acc[i][j]);
    }
    // all waves done READING buf[cur] before iteration kt+1 overwrites it.
    asm volatile("s_waitcnt lgkmcnt(0)\n\ts_barrier" ::: "memory");
  }

  if (n0 >= 2048) {
    // v band: transposed store, acc[i][j][0..3] = 4 consecutive rows (mi)
#pragma unroll
    for (int i = 0; i < 8; ++i) {
      int gm = m0 + wm + i * 16 + quad * 4;
      int p = gm >> 10, mi = gm & 1023;
#pragma unroll
      for (int j = 0; j < 4; ++j) {
        int vchan = (n0 + wn - 2048) + j * 16 + q15;
        bf16x4 pk = {(__bf16)acc[i][j][0], (__bf16)acc[i][j][1],
                     (__bf16)acc[i][j][2], (__bf16)acc[i][j][3]};
        *(bf16x4*)&vt[((((size_t)p << 10) | vchan) << 10) | mi] = pk;
      }
    }
    return;
  }

#pragma unroll
  for (int i = 0; i < 8; ++i)
#pragma unroll
    for (int r = 0; r < 4; ++r) {
      int gm = m0 + wm + i * 16 + quad * 4 + r;
      size_t rowo = (size_t)gm * 3072 + n0 + wn;
#pragma unroll
      for (int j = 0; j < 4; ++j) {
        int col = j * 16 + q15;
        Cb[rowo + col] = (__bf16)acc[i][j][r];
      }
    }
}

// ---------------------------------------------------------------------------
// R12: MFMA NT GEMM, 128x128 block tile — RESTORED (verbatim R4-era proven
// code) for the PROJ GEMM. gemm64's 64^2 tiles stage 2x the bytes/FLOP
// (proj: 2048 blocks x 256KB = 512MB staged for 17.2GF); at the ~5TB/s
// staging wall that's the likely hidden ~60-100us. 128^2: 512 blocks x
// 512KB = 256MB, 2 blocks/CU (32KB LDS), R4-measured ~442 TF structure.
// Per-output-element K order = it*32 + quad*8 ascending == gemm64's ->
// bit-identical proj output.
__global__ __launch_bounds__(256) void gemm_bf16_nt(const bf16* __restrict__ A,
                                                    const bf16* __restrict__ B,
                                                    bf16* __restrict__ Cb,
                                                    float* __restrict__ Cf,
                                                    const float* __restrict__ addend,
                                                    const float* __restrict__ bias,
                                                    bf16* __restrict__ vt,
                                                    int vt_col0,
                                                    int N) {
  __shared__ bf16 As[2][4][128][8];   // 16KB (double buffer)
  __shared__ bf16 Bs[2][4][128][8];   // 16KB
  size_t zoff = (size_t)blockIdx.z << 20;
  B += zoff;
  if (Cb) Cb += zoff;
  if (addend) addend += zoff;
  int t = threadIdx.x, w = t >> 6, lane = t & 63;
  int q15 = lane & 15, quad = lane >> 4;
  // XCD swizzle (bijective remap of the block grid; gridDim.y % 8 == 0)
  int lid = blockIdx.x + gridDim.x * blockIdx.y;
  int band = gridDim.y >> 3;
  int xcd = lid & 7, tt = lid >> 3;
  int by = xcd * band + tt % band;
  int bx = tt / band;
  int m0 = by * 128, n0 = bx * 128;
  int wm = (w >> 1) * 64, wn = (w & 1) * 64;
  floatx4 acc[4][4];
#pragma unroll
  for (int i = 0; i < 4; ++i)
#pragma unroll
    for (int j = 0; j < 4; ++j) acc[i][j] = (floatx4){0.f, 0.f, 0.f, 0.f};

  const bf16* Ag = A + (size_t)(m0 + lane) * 1024 + w * 8;
  const bf16* Bg = B + (size_t)(n0 + lane) * 1024 + w * 8;

  // prologue: stage K-step 0 into buffer 0
  async_load16(Ag,             &As[0][w][0][0]);
  async_load16(Ag + 64 * 1024, &As[0][w][64][0]);
  async_load16(Bg,             &Bs[0][w][0][0]);
  async_load16(Bg + 64 * 1024, &Bs[0][w][64][0]);

  for (int it = 0; it < 32; ++it) {
    int cur = it & 1;
    __syncthreads();   // drains loads(it) (issued one full compute phase ago)
    if (it + 1 < 32) {
      int k0 = (it + 1) * 32;
      async_load16(Ag + k0,             &As[cur ^ 1][w][0][0]);
      async_load16(Ag + 64 * 1024 + k0, &As[cur ^ 1][w][64][0]);
      async_load16(Bg + k0,             &Bs[cur ^ 1][w][0][0]);
      async_load16(Bg + 64 * 1024 + k0, &Bs[cur ^ 1][w][64][0]);
    }
    bf16x8 af[4], bfr[4];
#pragma unroll
    for (int i = 0; i < 4; ++i)
      af[i] = *(const bf16x8*)&As[cur][quad][wm + i * 16 + q15][0];
#pragma unroll
    for (int j = 0; j < 4; ++j)
      bfr[j] = *(const bf16x8*)&Bs[cur][quad][wn + j * 16 + q15][0];
#pragma unroll
    for (int i = 0; i < 4; ++i)
#pragma unroll
      for (int j = 0; j < 4; ++j) acc[i][j] = mfma16(af[i], bfr[j], acc[i][j]);
  }

  if (vt && (n0 + wn) >= vt_col0) {
#pragma unroll
    for (int i = 0; i < 4; ++i) {
      int gm = m0 + wm + i * 16 + quad * 4;          // row (4 consecutive)
      int p = gm >> 10, mi = gm & 1023;
#pragma unroll
      for (int j = 0; j < 4; ++j) {
        int vchan = (n0 + wn - vt_col0) + j * 16 + q15;
        bf16x4 pk = {(__bf16)acc[i][j][0], (__bf16)acc[i][j][1],
                     (__bf16)acc[i][j][2], (__bf16)acc[i][j][3]};
        *(bf16x4*)&vt[((((size_t)p << 10) | vchan) << 10) | mi] = pk;
      }
    }
    return;
  }

#pragma unroll
  for (int i = 0; i < 4; ++i)
#pragma unroll
    for (int r = 0; r < 4; ++r) {
      int gm = m0 + wm + i * 16 + quad * 4 + r;
      size_t rowo = (size_t)gm * N + n0 + wn;
#pragma unroll
      for (int j = 0; j < 4; ++j) {
        int col = j * 16 + q15;
        float v = acc[i][j][r];
        if (Cf) {
          Cf[rowo + col] = v + (bias ? bias[n0 + wn + col] : 0.f);
        } else {
          if (addend) v += addend[rowo + col];
          Cb[rowo + col] = (__bf16)v;
        }
      }
    }
}

// ---------------------------------------------------------------------------
// MFMA NT GEMM, 64x64 block tile — for the SMALL LoRA GEMMs only now
// (their M/N are too small for 128-tile grids).
__global__ __launch_bounds__(256) void gemm64_bf16_nt(const bf16* __restrict__ A,
                                                      const bf16* __restrict__ B,
                                                      bf16* __restrict__ Cb,
                                                      float* __restrict__ Cf,
                                                      const float* __restrict__ addend,
                                                      const float* __restrict__ bias,
                                                      bf16* __restrict__ vt,
                                                      int vt_col0,
                                                      int N) {
  __shared__ bf16 As[2][4][64][8];   // 8KB (double buffer)
  __shared__ bf16 Bs[2][4][64][8];   // 8KB
  size_t zoff = (size_t)blockIdx.z << 20;
  B += zoff;
  if (Cb) Cb += zoff;
  if (addend) addend += zoff;
  int t = threadIdx.x, w = t >> 6, lane = t & 63;
  int q15 = lane & 15, quad = lane >> 4;
  // XCD swizzle (bijective; gridDim.y % 8 == 0 for all our grids)
  int lid = blockIdx.x + gridDim.x * blockIdx.y;
  int band = gridDim.y >> 3;
  int xcd = lid & 7, tt = lid >> 3;
  int by = xcd * band + tt % band;
  int bx = tt / band;
  int m0 = by * 64, n0 = bx * 64;
  int wm = (w >> 1) * 32, wn = (w & 1) * 32;
  floatx4 acc[2][2];
#pragma unroll
  for (int i = 0; i < 2; ++i)
#pragma unroll
    for (int j = 0; j < 2; ++j) acc[i][j] = (floatx4){0.f, 0.f, 0.f, 0.f};

  const bf16* Ag = A + (size_t)(m0 + lane) * 1024 + w * 8;
  const bf16* Bg = B + (size_t)(n0 + lane) * 1024 + w * 8;

  // prologue: stage K-step 0 into buffer 0 (wave w stages kchunk w, 64 rows)
  async_load16(Ag, &As[0][w][0][0]);
  async_load16(Bg, &Bs[0][w][0][0]);

  for (int it = 0; it < 32; ++it) {
    int cur = it & 1;
    __syncthreads();   // drains loads(it)
    if (it + 1 < 32) {
      int k0 = (it + 1) * 32;
      async_load16(Ag + k0, &As[cur ^ 1][w][0][0]);
      async_load16(Bg + k0, &Bs[cur ^ 1][w][0][0]);
    }
    bf16x8 af[2], bfr[2];
#pragma unroll
    for (int i = 0; i < 2; ++i)
      af[i] = *(const bf16x8*)&As[cur][quad][wm + i * 16 + q15][0];
#pragma unroll
    for (int j = 0; j < 2; ++j)
      bfr[j] = *(const bf16x8*)&Bs[cur][quad][wn + j * 16 + q15][0];
#pragma unroll
    for (int i = 0; i < 2; ++i)
#pragma unroll
      for (int j = 0; j < 2; ++j) acc[i][j] = mfma16(af[i], bfr[j], acc[i][j]);
  }

  if (vt && (n0 + wn) >= vt_col0) {
#pragma unroll
    for (int i = 0; i < 2; ++i) {
      int gm = m0 + wm + i * 16 + quad * 4;          // row (4 consecutive)
      int p = gm >> 10, mi = gm & 1023;
#pragma unroll
      for (int j = 0; j < 2; ++j) {
        int vchan = (n0 + wn - vt_col0) + j * 16 + q15;
        bf16x4 pk = {(__bf16)acc[i][j][0], (__bf16)acc[i][j][1],
                     (__bf16)acc[i][j][2], (__bf16)acc[i][j][3]};
        *(bf16x4*)&vt[((((size_t)p << 10) | vchan) << 10) | mi] = pk;
      }
    }
    return;
  }

#pragma unroll
  for (int i = 0; i < 2; ++i)
#pragma unroll
    for (int r = 0; r < 4; ++r) {
      int gm = m0 + wm + i * 16 + quad * 4 + r;
      size_t rowo = (size_t)gm * N + n0 + wn;
#pragma unroll
      for (int j = 0; j < 2; ++j) {
        int col = j * 16 + q15;
        float v = acc[i][j][r];
        if (Cf) {
          Cf[rowo + col] = v + (bias ? bias[n0 + wn + col] : 0.f);
        } else {
          if (addend) v += addend[rowo + col];
          Cb[rowo + col] = (__bf16)v;
        }
      }
    }
}

// ---------------------------------------------------------------------------
// Flash attention, S^T formulation (R9 structure). Block = (b,h,128 q rows),
// 4 waves. Q fragments in registers; PsB aliases dead Qs; K/V double-buffered
// with cross-barrier prefetch, one barrier per kv-tile. No online softmax
// (logits pre-scaled by 0.125*log2e, bounded). XCD swizzle keeps a (b,h)'s
// q-tiles on one XCD.
__global__ __launch_bounds__(256) void attn_mfma(const bf16* __restrict__ qkvb,
                                                 const bf16* __restrict__ Vt,
                                                 bf16* __restrict__ attn_out) {
  __shared__ __align__(16) char smem[49152];
  bf16 (*Qs)[128][8] = (bf16(*)[128][8])smem;              // [8][128][8] 16KB
  bf16* PsB = (bf16*)smem;                                 // aliases Qs after prologue
  bf16 (*Ks)[8][64][8] = (bf16(*)[8][64][8])(smem + 16384); // [2][8][64][8] 16KB
  bf16 (*Vs)[8][64][8] = (bf16(*)[8][64][8])(smem + 32768); // [2][8][64][8] 16KB

  int t = threadIdx.x, w = t >> 6, lane = t & 63;
  int q15 = lane & 15, quad = lane >> 4;
  int lid = blockIdx.x + (blockIdx.y << 3);
  int xcd = lid & 7, rr = lid >> 3;
  int q0 = (rr & 7) * 128;
  int bh = xcd + ((rr >> 3) << 3);
  int b = bh >> 4, h = bh & 15;

  const bf16* Qg = qkvb + (size_t)(b * 1024 + q0) * 3072 + h * 64;
  const bf16* Kg = qkvb + (size_t)(b * 1024) * 3072 + 1024 + h * 64;
  const bf16* Vg = Vt + (size_t)(bh * 64) * 1024;

  // prologue: stage Q tile + K/V tile 0 (buffer 0)
#pragma unroll
  for (int cc = 0; cc < 2; ++cc) {
    int kc = w * 2 + cc;
    async_load16(Qg + (size_t)lane * 3072 + kc * 8,        &Qs[kc][0][0]);
    async_load16(Qg + (size_t)(64 + lane) * 3072 + kc * 8, &Qs[kc][64][0]);
  }
  {
    const bf16* Kg2 = Kg + (size_t)lane * 3072;
    const bf16* Vg2 = Vg + (size_t)lane * 1024;
    async_load16(Kg2 + (w * 2) * 8,     &Ks[0][w * 2][0][0]);
    async_load16(Kg2 + (w * 2 + 1) * 8, &Ks[0][w * 2 + 1][0][0]);
    async_load16(Vg2 + (w * 2) * 8,     &Vs[0][w * 2][0][0]);
    async_load16(Vg2 + (w * 2 + 1) * 8, &Vs[0][w * 2 + 1][0][0]);
  }
  __syncthreads();

  // hoist Q fragments (invariant over kv loop)
  bf16x8 qfr[2][2];
#pragma unroll
  for (int ks = 0; ks < 2; ++ks)
#pragma unroll
    for (int nt = 0; nt < 2; ++nt)
      qfr[ks][nt] = *(const bf16x8*)&Qs[ks * 4 + quad][w * 32 + nt * 16 + q15][0];

  floatx4 oacc[4][2];
  float l_i[2] = {0.f, 0.f};
#pragma unroll
  for (int nt = 0; nt < 2; ++nt)
#pragma unroll
    for (int mt = 0; mt < 4; ++mt) oacc[mt][nt] = (floatx4){0.f, 0.f, 0.f, 0.f};

  for (int kt = 0; kt < 16; ++kt) {
    int cur = kt & 1;
    __syncthreads();   // drains prefetch(kt); at kt=0 also fences Qs->PsB reuse
    if (kt + 1 < 16) {
      int kv0n = (kt + 1) * 64;
      const bf16* Kg3 = Kg + (size_t)(kv0n + lane) * 3072;
      const bf16* Vg3 = Vg + (size_t)lane * 1024 + kv0n;
      async_load16(Kg3 + (w * 2) * 8,     &Ks[cur ^ 1][w * 2][0][0]);
      async_load16(Kg3 + (w * 2 + 1) * 8, &Ks[cur ^ 1][w * 2 + 1][0][0]);
      async_load16(Vg3 + (w * 2) * 8,     &Vs[cur ^ 1][w * 2][0][0]);
      async_load16(Vg3 + (w * 2 + 1) * 8, &Vs[cur ^ 1][w * 2 + 1][0][0]);
    }

    // S^T = K Q^T
    floatx4 sacc[4][2];
#pragma unroll
    for (int mt = 0; mt < 4; ++mt)
#pragma unroll
      for (int nt = 0; nt < 2; ++nt) sacc[mt][nt] = (floatx4){0.f, 0.f, 0.f, 0.f};
#pragma unroll
    for (int ks = 0; ks < 2; ++ks) {
      bf16x8 kf[4];
#pragma unroll
      for (int mt = 0; mt < 4; ++mt)
        kf[mt] = *(const bf16x8*)&Ks[cur][ks * 4 + quad][mt * 16 + q15][0];
#pragma unroll
      for (int mt = 0; mt < 4; ++mt)
#pragma unroll
        for (int nt = 0; nt < 2; ++nt)
          sacc[mt][nt] = mfma16(kf[mt], qfr[ks][nt], sacc[mt][nt]);
    }

    // softmax numerator: p = exp2(s) (no max/rescale; logits bounded)
#pragma unroll
    for (int nt = 0; nt < 2; ++nt) {
      float rsum = 0.f;
#pragma unroll
      for (int mt = 0; mt < 4; ++mt)
#pragma unroll
        for (int r = 0; r < 4; ++r) {
          float p = fexp2(sacc[mt][nt][r]);
          sacc[mt][nt][r] = p;
          rsum += p;
        }
      rsum += __shfl_xor(rsum, 16);
      rsum += __shfl_xor(rsum, 32);
      l_i[nt] += rsum;
    }

    // P^T -> per-wave LDS region (B-frag layout), same-wave RAW via lgkmcnt
#pragma unroll
    for (int nt = 0; nt < 2; ++nt)
#pragma unroll
      for (int mt = 0; mt < 4; ++mt) {
        bf16x4 pk = {(__bf16)sacc[mt][nt][0], (__bf16)sacc[mt][nt][1],
                     (__bf16)sacc[mt][nt][2], (__bf16)sacc[mt][nt][3]};
        int kc = mt * 2 + (quad >> 1);
        *(bf16x4*)&PsB[(size_t)(w * 2 + nt) * 1024 + kc * 128 + q15 * 8 + (quad & 1) * 4] = pk;
      }

    // O^T += V^T P^T
#pragma unroll
    for (int ks = 0; ks < 2; ++ks) {
      bf16x8 vf[4], pf[2];
#pragma unroll
      for (int mt = 0; mt < 4; ++mt)
        vf[mt] = *(const bf16x8*)&Vs[cur][ks * 4 + quad][mt * 16 + q15][0];
#pragma unroll
      for (int nt = 0; nt < 2; ++nt)
        pf[nt] = *(const bf16x8*)&PsB[(size_t)(w * 2 + nt) * 1024 + (ks * 4 + quad) * 128 + q15 * 8];
#pragma unroll
      for (int mt = 0; mt < 4; ++mt)
#pragma unroll
        for (int nt = 0; nt < 2; ++nt) oacc[mt][nt] = mfma16(vf[mt], pf[nt], oacc[mt][nt]);
    }
  }

  __syncthreads();
  bf16* T = (bf16*)smem + w * 2304;   // [32 q][72]; overlaps dead Qs/PsB + Ks head
#pragma unroll
  for (int nt = 0; nt < 2; ++nt) {
    float inv = 1.f / l_i[nt];
#pragma unroll
    for (int mt = 0; mt < 4; ++mt) {
      bf16x4 pk = {(__bf16)(oacc[mt][nt][0] * inv), (__bf16)(oacc[mt][nt][1] * inv),
                   (__bf16)(oacc[mt][nt][2] * inv), (__bf16)(oacc[mt][nt][3] * inv)};
      *(bf16x4*)&T[(nt * 16 + q15) * 72 + mt * 16 + quad * 4] = pk;
    }
  }
  __syncthreads();
  int row = lane >> 1, ch = (lane & 1) * 32;
  const bf16* Tr = T + row * 72 + ch;
  bf16* outp = attn_out + (size_t)(b * 1024 + q0 + w * 32 + row) * 1024 + h * 64 + ch;
#pragma unroll
  for (int i = 0; i < 4; ++i) *(bf16x8*)&outp[i * 8] = *(const bf16x8*)&Tr[i * 8];
}

// ---------------------------------------------------------------------------
extern "C" void kernel_launch(void* const* d_in, const int* in_sizes, int n_in,
                              void* d_out, int out_size, void* d_ws, size_t ws_size,
                              hipStream_t stream) {
  (void)in_sizes; (void)n_in; (void)out_size; (void)ws_size;
  const float* x       = (const float*)d_in[0];   // 8x1024x1024
  const float* W_qkv   = (const float*)d_in[1];   // 3072x1024
  const float* W_proj  = (const float*)d_in[2];   // 1024x1024
  const float* b_proj  = (const float*)d_in[3];   // 1024
  const float* coef_k  = (const float*)d_in[4];   // 10x3000
  const float* coef_v  = (const float*)d_in[5];   // 10x3000
  const int*   indices = (const int*)d_in[6];     // 10x3000
  const int*   task    = (const int*)d_in[7];     // scalar

  // Workspace (106 MB peak). attn_out aliases the dead Sf/S2b/Tt region.
  char* w8 = (char*)d_ws;
  float* Sf     = (float*)(w8);                   // 8MB  (2 fp32 planes, transient)
  bf16*  S2b    = (bf16*) (w8 + (8u  << 20));     // 4MB  [2048][1024] (transient)
  bf16*  Tt     = (bf16*) (w8 + (12u << 20));     // 4MB  [2][1024][1024] (transient)
  bf16*  Bmtb   = (bf16*) (w8 + (16u << 20));     // 2MB
  bf16*  Wcb    = (bf16*) (w8 + (18u << 20));     // 6MB  [3072][1024]
  bf16*  xb     = (bf16*) (w8 + (24u << 20));     // 16MB
  bf16*  qkvb   = (bf16*) (w8 + (40u << 20));     // 48MB [8192][3072]
  bf16*  Vt     = (bf16*) (w8 + (88u << 20));     // 16MB [128][64][1024]
  bf16*  Wprojb = (bf16*) (w8 + (104u << 20));    // 2MB
  bf16*  attnout= (bf16*) (w8);                   // 16MB alias (Sf/S2b/Tt dead)

  // Dense S scatter (fp32 planes), then ONE merged prep launch
  hipMemsetAsync(Sf, 0, (size_t)8 << 20, stream);
  scatter_s<<<118, 256, 0, stream>>>(coef_k, coef_v, indices, task, Sf);
  prep_kernel<<<13312, 256, 0, stream>>>(W_qkv, W_proj, x, Sf,
                                         Bmtb, Wcb, Wprojb, xb, S2b);

  // LoRA: T = S @ Bm (stored transposed per plane), then both band GEMMs
  gemm64_bf16_nt<<<dim3(16, 32), 256, 0, stream>>>(S2b, Bmtb, nullptr, nullptr,
                                                   nullptr, nullptr, Tt, 0, 1024);
  gemm64_bf16_nt<<<dim3(16, 16, 2), 256, 0, stream>>>(Bmtb, Tt, Wcb + (1u << 20), nullptr,
                                                      W_qkv + (1u << 20), nullptr, nullptr,
                                                      1 << 30, 1024);

  // qkv = xb @ Wcb^T -> q,k bands bf16 into qkvb; v band transposed into Vt.
  // R12: reverted to the R6 measured-best kernel (77.5us).
  gemm256_qkv<<<dim3(12, 32), 512, 0, stream>>>(xb, Wcb, qkvb, Vt);

  // attention
  attn_mfma<<<dim3(8, 128), 256, 0, stream>>>(qkvb, Vt, attnout);

  // out = attn_out @ W_proj^T + b_proj  (fp32 out)
  // R12: 128^2-tile kernel (512 blocks, 2/CU, half the staged bytes/FLOP
  // of gemm64's 64^2 tiles).
  gemm_bf16_nt<<<dim3(8, 64), 256, 0, stream>>>(attnout, Wprojb, nullptr, (float*)d_out,
                                                nullptr, b_proj, nullptr, 1 << 30, 1024);
}

// Round 14
// 304.313 us; speedup vs baseline: 1.8058x; 1.0611x over previous
//
#include <hip/hip_runtime.h>
#include <math.h>

// B=8, N=1024, C=1024, H=16, hd=64, n_tasks=10, n_frq=3000
#define NFRQ 3000

typedef __bf16 bf16;
typedef __attribute__((ext_vector_type(8))) __bf16 bf16x8;
typedef __attribute__((ext_vector_type(4))) __bf16 bf16x4;
typedef __attribute__((ext_vector_type(4))) float floatx4;

__device__ __forceinline__ floatx4 mfma16(bf16x8 a, bf16x8 b, floatx4 c) {
  return __builtin_amdgcn_mfma_f32_16x16x32_bf16(a, b, c, 0, 0, 0);
}

// async global->LDS, 16B per lane, dest = base + lane*16.
__device__ __forceinline__ void async_load16(const bf16* g, bf16* l) {
  __builtin_amdgcn_global_load_lds(
      (const __attribute__((address_space(1))) unsigned int*)g,
      (__attribute__((address_space(3))) unsigned int*)l, 16, 0, 0);
}

__device__ __forceinline__ float fexp2(float x) {
  return __builtin_amdgcn_exp2f(x);
}

// ---------------------------------------------------------------------------
// Merged prep: DCT basis + 4 fp32->bf16 conversions in ONE launch.
__global__ __launch_bounds__(256) void prep_kernel(
    const float* __restrict__ W_qkv, const float* __restrict__ W_proj,
    const float* __restrict__ x, const float* __restrict__ Sf,
    bf16* __restrict__ Bmtb, bf16* __restrict__ Wcbq,
    bf16* __restrict__ Wprojb, bf16* __restrict__ xb,
    bf16* __restrict__ S2b) {
  int r = blockIdx.x;
  if (r < 1024) {
    // DCT-II transposed bf16: out[t]=Bm[i][j] with j=t>>10,i=t&1023 (4/thread)
    int base = r * 1024 + (int)threadIdx.x * 4;
    const float cst = 0.04419417382415922f;  // sqrt(2)/32
    const float w = 1.5339807878856412e-3f;  // pi/2048
    bf16x4 o;
#pragma unroll
    for (int u = 0; u < 4; ++u) {
      int t = base + u;
      int j = t >> 10, i = t & 1023;
      int K = (i * (2 * j + 1)) & 4095;
      float v = (i == 0) ? 0.03125f : cst * __cosf((float)K * w);
      o[u] = (__bf16)v;
    }
    *(bf16x4*)&Bmtb[base] = o;
    return;
  }
  const float* src;
  bf16* dst;
  float scale = 1.0f;
  int i;
  if (r < 2048) {
    i = (r - 1024) * 256 + threadIdx.x;
    src = W_qkv; dst = Wcbq;
    scale = 0.18033688011112042f;  // 0.125 * log2(e)
  } else if (r < 3072) {
    i = (r - 2048) * 256 + threadIdx.x;
    src = W_proj; dst = Wprojb;
  } else if (r < 11264) {
    i = (r - 3072) * 256 + threadIdx.x;
    src = x; dst = xb;
  } else {
    i = (r - 11264) * 256 + threadIdx.x;
    src = Sf; dst = S2b;
  }
  float4 f = ((const float4*)src)[i];
  bf16x4 o = {(__bf16)(f.x * scale), (__bf16)(f.y * scale),
              (__bf16)(f.z * scale), (__bf16)(f.w * scale)};
  *(bf16x4*)&dst[(size_t)i * 4] = o;
}

// ---------------------------------------------------------------------------
// Dense scatter: S[id] += coef (2 fp32 planes, k and v). One thread per nz.
__global__ __launch_bounds__(256) void scatter_s(const float* __restrict__ coef_k,
                                                 const float* __restrict__ coef_v,
                                                 const int* __restrict__ idx,
                                                 const int* __restrict__ task,
                                                 float* __restrict__ S) {
  int nz = blockIdx.x * 256 + threadIdx.x;
  if (nz >= 10 * NFRQ || nz >= (*task + 1) * NFRQ) return;
  int id = idx[nz];
  atomicAdd(S + id, coef_k[nz]);
  atomicAdd(S + (1u << 20) + id, coef_v[nz]);
}

// ---------------------------------------------------------------------------
// qkv GEMM: R6 measured-best (77.5us). 256x256, BK=64, 128KB LDS, coalesced
// row-major staging + XOR swizzle (rule #21 both-sides), 2-barrier
// counted-vmcnt loop. Structure attempts R7/R10/R11 all regressed; floor
// here ≈ 384MB staged at ~20GB/s/CU fabric rate. Outputs bit-identical
// across variants (absmax exactly 0.0546875 every passing run).
__global__ __launch_bounds__(512, 2) void gemm256_qkv(const bf16* __restrict__ A,
                                                      const bf16* __restrict__ B,
                                                      bf16* __restrict__ Cb,
                                                      bf16* __restrict__ vt) {
  __shared__ bf16 As[2][256][64];   // 64KB (double buffer, row-major LD=64)
  __shared__ bf16 Bs[2][256][64];   // 64KB
  int t = threadIdx.x, w = t >> 6, lane = t & 63;
  int q15 = lane & 15, quad = lane >> 4;
  // XCD swizzle (bijective; gridDim.y = 32, band = 4)
  int lid = blockIdx.x + gridDim.x * blockIdx.y;
  int band = gridDim.y >> 3;
  int xcd = lid & 7, tt = lid >> 3;
  int by = xcd * band + tt % band;
  int bx = tt / band;
  int m0 = by * 256, n0 = bx * 256;
  int wm = (w >> 2) * 128, wn = (w & 3) * 64;

  floatx4 acc[8][4];
#pragma unroll
  for (int i = 0; i < 8; ++i)
#pragma unroll
    for (int j = 0; j < 4; ++j) acc[i][j] = (floatx4){0.f, 0.f, 0.f, 0.f};

  // Staging: inst s covers tile-rows [s*8, s*8+8). Lane l -> sub-row
  // sr=l>>3, chunk sc=l&7; global k-chunk = sc^sr (lane-constant).
  int sr = lane >> 3, sc = lane & 7;
  const bf16* Agl = A + (size_t)(m0 + sr) * 1024 + (sc ^ sr) * 8;
  const bf16* Bgl = B + (size_t)(n0 + sr) * 1024 + (sc ^ sr) * 8;

  // prologue: stage K-tile 0 into buffer 0 (8 insts/wave: 4 A + 4 B)
#pragma unroll
  for (int s = 0; s < 4; ++s) {
    int rb = w * 32 + s * 8;
    async_load16(Agl + (size_t)rb * 1024, &As[0][rb][0]);
    async_load16(Bgl + (size_t)rb * 1024, &Bs[0][rb][0]);
  }

  for (int kt = 0; kt < 16; ++kt) {
    int cur = kt & 1;
    if (kt + 1 < 16) {
      int k0 = (kt + 1) * 64;
#pragma unroll
      for (int s = 0; s < 4; ++s) {
        int rb = w * 32 + s * 8;
        async_load16(Agl + (size_t)rb * 1024 + k0, &As[cur ^ 1][rb][0]);
        async_load16(Bgl + (size_t)rb * 1024 + k0, &Bs[cur ^ 1][rb][0]);
      }
      asm volatile("s_waitcnt vmcnt(8)\n\ts_barrier" ::: "memory");
    } else {
      asm volatile("s_waitcnt vmcnt(0)\n\ts_barrier" ::: "memory");
    }
    int rp = q15 & 7;
#pragma unroll
    for (int kk = 0; kk < 2; ++kk) {
      int kc = kk * 4 + quad;
      int ksw = (kc ^ rp) * 8;
      bf16x8 af[8], bfr[4];
#pragma unroll
      for (int i = 0; i < 8; ++i)
        af[i] = *(const bf16x8*)&As[cur][wm + i * 16 + q15][ksw];
#pragma unroll
      for (int j = 0; j < 4; ++j)
        bfr[j] = *(const bf16x8*)&Bs[cur][wn + j * 16 + q15][ksw];
#pragma unroll
      for (int i = 0; i < 8; ++i)
#pragma unroll
        for (int j = 0; j < 4; ++j)
          acc[i][j] = mfma16(af[i], bfr[j], acc[i][j]);
    }
    asm volatile("s_waitcnt lgkmcnt(0)\n\ts_barrier" ::: "memory");
  }

  if (n0 >= 2048) {
    // v band: transposed store, acc[i][j][0..3] = 4 consecutive rows (mi)
#pragma unroll
    for (int i = 0; i < 8; ++i) {
      int gm = m0 + wm + i * 16 + quad * 4;
      int p = gm >> 10, mi = gm & 1023;
#pragma unroll
      for (int j = 0; j < 4; ++j) {
        int vchan = (n0 + wn - 2048) + j * 16 + q15;
        bf16x4 pk = {(__bf16)acc[i][j][0], (__bf16)acc[i][j][1],
                     (__bf16)acc[i][j][2], (__bf16)acc[i][j][3]};
        *(bf16x4*)&vt[((((size_t)p << 10) | vchan) << 10) | mi] = pk;
      }
    }
    return;
  }

#pragma unroll
  for (int i = 0; i < 8; ++i)
#pragma unroll
    for (int r = 0; r < 4; ++r) {
      int gm = m0 + wm + i * 16 + quad * 4 + r;
      size_t rowo = (size_t)gm * 3072 + n0 + wn;
#pragma unroll
      for (int j = 0; j < 4; ++j) {
        int col = j * 16 + q15;
        Cb[rowo + col] = (__bf16)acc[i][j][r];
      }
    }
}

// ---------------------------------------------------------------------------
// R13: PROJ GEMM, 256x128 tile, ONE-ROUND grid (8x32 = 256 blocks = exactly
// 1 block/CU, no tail round). Clone of the proven gemm256_qkv loop with
// BN=128: 8 waves each 128x32 (acc[8][2]); staging 4 A + 2 B insts/wave
// per tile -> steady vmcnt(6); same XOR swizzle; LDS 96KB (As 64 + Bs 32).
// Staged bytes 192MB (vs 256MB for the R12 128^2 kernel at 512 blocks).
// K accumulation: ascending 32-wide MFMA windows (kt*64 + kk*32), exactly
// the same per-output-element order as before -> bit-identical proj output.
// Epilogue: fp32 + bias (proj is the only user).
__global__ __launch_bounds__(512) void gemm256_proj(const bf16* __restrict__ A,
                                                    const bf16* __restrict__ B,
                                                    float* __restrict__ Cf,
                                                    const float* __restrict__ bias) {
  __shared__ bf16 As[2][256][64];   // 64KB
  __shared__ bf16 Bs[2][128][64];   // 32KB
  int t = threadIdx.x, w = t >> 6, lane = t & 63;
  int q15 = lane & 15, quad = lane >> 4;
  // XCD swizzle (bijective; gridDim.y = 32, band = 4)
  int lid = blockIdx.x + gridDim.x * blockIdx.y;
  int band = gridDim.y >> 3;
  int xcd = lid & 7, tt = lid >> 3;
  int by = xcd * band + tt % band;
  int bx = tt / band;
  int m0 = by * 256, n0 = bx * 128;
  int wm = (w >> 2) * 128, wn = (w & 3) * 32;

  floatx4 acc[8][2];
#pragma unroll
  for (int i = 0; i < 8; ++i)
#pragma unroll
    for (int j = 0; j < 2; ++j) acc[i][j] = (floatx4){0.f, 0.f, 0.f, 0.f};

  int sr = lane >> 3, sc = lane & 7;
  const bf16* Agl = A + (size_t)(m0 + sr) * 1024 + (sc ^ sr) * 8;
  const bf16* Bgl = B + (size_t)(n0 + sr) * 1024 + (sc ^ sr) * 8;

  // prologue: 6 insts/wave (4 A rows w*32+s*8, 2 B rows w*16+s*8)
#pragma unroll
  for (int s = 0; s < 4; ++s)
    async_load16(Agl + (size_t)(w * 32 + s * 8) * 1024, &As[0][w * 32 + s * 8][0]);
#pragma unroll
  for (int s = 0; s < 2; ++s)
    async_load16(Bgl + (size_t)(w * 16 + s * 8) * 1024, &Bs[0][w * 16 + s * 8][0]);

  for (int kt = 0; kt < 16; ++kt) {
    int cur = kt & 1;
    if (kt + 1 < 16) {
      int k0 = (kt + 1) * 64;
#pragma unroll
      for (int s = 0; s < 4; ++s)
        async_load16(Agl + (size_t)(w * 32 + s * 8) * 1024 + k0,
                     &As[cur ^ 1][w * 32 + s * 8][0]);
#pragma unroll
      for (int s = 0; s < 2; ++s)
        async_load16(Bgl + (size_t)(w * 16 + s * 8) * 1024 + k0,
                     &Bs[cur ^ 1][w * 16 + s * 8][0]);
      asm volatile("s_waitcnt vmcnt(6)\n\ts_barrier" ::: "memory");
    } else {
      asm volatile("s_waitcnt vmcnt(0)\n\ts_barrier" ::: "memory");
    }
    int rp = q15 & 7;
#pragma unroll
    for (int kk = 0; kk < 2; ++kk) {
      int kc = kk * 4 + quad;
      int ksw = (kc ^ rp) * 8;
      bf16x8 af[8], bfr[2];
#pragma unroll
      for (int i = 0; i < 8; ++i)
        af[i] = *(const bf16x8*)&As[cur][wm + i * 16 + q15][ksw];
#pragma unroll
      for (int j = 0; j < 2; ++j)
        bfr[j] = *(const bf16x8*)&Bs[cur][wn + j * 16 + q15][ksw];
#pragma unroll
      for (int i = 0; i < 8; ++i)
#pragma unroll
        for (int j = 0; j < 2; ++j)
          acc[i][j] = mfma16(af[i], bfr[j], acc[i][j]);
    }
    asm volatile("s_waitcnt lgkmcnt(0)\n\ts_barrier" ::: "memory");
  }

#pragma unroll
  for (int i = 0; i < 8; ++i)
#pragma unroll
    for (int r = 0; r < 4; ++r) {
      int gm = m0 + wm + i * 16 + quad * 4 + r;
      size_t rowo = (size_t)gm * 1024 + n0 + wn;
#pragma unroll
      for (int j = 0; j < 2; ++j) {
        int col = j * 16 + q15;
        Cf[rowo + col] = acc[i][j][r] + bias[n0 + wn + col];
      }
    }
}

// ---------------------------------------------------------------------------
// MFMA NT GEMM, 64x64 block tile — for the SMALL LoRA GEMMs.
__global__ __launch_bounds__(256) void gemm64_bf16_nt(const bf16* __restrict__ A,
                                                      const bf16* __restrict__ B,
                                                      bf16* __restrict__ Cb,
                                                      float* __restrict__ Cf,
                                                      const float* __restrict__ addend,
                                                      const float* __restrict__ bias,
                                                      bf16* __restrict__ vt,
                                                      int vt_col0,
                                                      int N) {
  __shared__ bf16 As[2][4][64][8];   // 8KB (double buffer)
  __shared__ bf16 Bs[2][4][64][8];   // 8KB
  size_t zoff = (size_t)blockIdx.z << 20;
  B += zoff;
  if (Cb) Cb += zoff;
  if (addend) addend += zoff;
  int t = threadIdx.x, w = t >> 6, lane = t & 63;
  int q15 = lane & 15, quad = lane >> 4;
  int lid = blockIdx.x + gridDim.x * blockIdx.y;
  int band = gridDim.y >> 3;
  int xcd = lid & 7, tt = lid >> 3;
  int by = xcd * band + tt % band;
  int bx = tt / band;
  int m0 = by * 64, n0 = bx * 64;
  int wm = (w >> 1) * 32, wn = (w & 1) * 32;
  floatx4 acc[2][2];
#pragma unroll
  for (int i = 0; i < 2; ++i)
#pragma unroll
    for (int j = 0; j < 2; ++j) acc[i][j] = (floatx4){0.f, 0.f, 0.f, 0.f};

  const bf16* Ag = A + (size_t)(m0 + lane) * 1024 + w * 8;
  const bf16* Bg = B + (size_t)(n0 + lane) * 1024 + w * 8;

  async_load16(Ag, &As[0][w][0][0]);
  async_load16(Bg, &Bs[0][w][0][0]);

  for (int it = 0; it < 32; ++it) {
    int cur = it & 1;
    __syncthreads();
    if (it + 1 < 32) {
      int k0 = (it + 1) * 32;
      async_load16(Ag + k0, &As[cur ^ 1][w][0][0]);
      async_load16(Bg + k0, &Bs[cur ^ 1][w][0][0]);
    }
    bf16x8 af[2], bfr[2];
#pragma unroll
    for (int i = 0; i < 2; ++i)
      af[i] = *(const bf16x8*)&As[cur][quad][wm + i * 16 + q15][0];
#pragma unroll
    for (int j = 0; j < 2; ++j)
      bfr[j] = *(const bf16x8*)&Bs[cur][quad][wn + j * 16 + q15][0];
#pragma unroll
    for (int i = 0; i < 2; ++i)
#pragma unroll
      for (int j = 0; j < 2; ++j) acc[i][j] = mfma16(af[i], bfr[j], acc[i][j]);
  }

  if (vt && (n0 + wn) >= vt_col0) {
#pragma unroll
    for (int i = 0; i < 2; ++i) {
      int gm = m0 + wm + i * 16 + quad * 4;
      int p = gm >> 10, mi = gm & 1023;
#pragma unroll
      for (int j = 0; j < 2; ++j) {
        int vchan = (n0 + wn - vt_col0) + j * 16 + q15;
        bf16x4 pk = {(__bf16)acc[i][j][0], (__bf16)acc[i][j][1],
                     (__bf16)acc[i][j][2], (__bf16)acc[i][j][3]};
        *(bf16x4*)&vt[((((size_t)p << 10) | vchan) << 10) | mi] = pk;
      }
    }
    return;
  }

#pragma unroll
  for (int i = 0; i < 2; ++i)
#pragma unroll
    for (int r = 0; r < 4; ++r) {
      int gm = m0 + wm + i * 16 + quad * 4 + r;
      size_t rowo = (size_t)gm * N + n0 + wn;
#pragma unroll
      for (int j = 0; j < 2; ++j) {
        int col = j * 16 + q15;
        float v = acc[i][j][r];
        if (Cf) {
          Cf[rowo + col] = v + (bias ? bias[n0 + wn + col] : 0.f);
        } else {
          if (addend) v += addend[rowo + col];
          Cb[rowo + col] = (__bf16)v;
        }
      }
    }
}

// ---------------------------------------------------------------------------
// Flash attention, S^T formulation. Block = (b,h,128 q rows), 4 waves.
// R13: V SINGLE-BUFFERED -> LDS 48KB -> 40KB -> 4 blocks/CU (was 3 + a
// 256-block tail round; makespan ~6x solo-block vs 4x ideal). V(kt+1) is
// now staged AFTER PV(kt) behind a post-PV {lgkmcnt(0); s_barrier} (all
// waves' vf ds_reads complete before overwrite); its latency hides under
// iteration kt+1's QK phase via counted vmcnt. Ledger (per wave, steady):
//  top of kt:  outstanding = K(kt):2 older + V(kt):2 newer -> vmcnt(2)
//              waits K(kt) only; +lgkmcnt(0) fences cross-wave LDS reuse
//              (Qs->PsB at kt=0, Ks buffer recycling otherwise).
//  mid of kt:  outstanding = V(kt):2 older + K(kt+1):2 newer -> vmcnt(2)
//              (kt=15: no K prefetch -> vmcnt(0)) waits V(kt); barrier
//              publishes all waves' V chunks before PV.
//  post-PV:    lgkmcnt(0)+barrier, then stage V(kt+1) (skip at kt=15).
// All barriers wave-uniform. Math/accumulation order untouched ->
// bit-identical output (absmax must stay exactly 0.0546875).
__global__ __launch_bounds__(256) void attn_mfma(const bf16* __restrict__ qkvb,
                                                 const bf16* __restrict__ Vt,
                                                 bf16* __restrict__ attn_out) {
  __shared__ __align__(16) char smem[40960];
  bf16 (*Qs)[128][8] = (bf16(*)[128][8])smem;              // [8][128][8] 16KB
  bf16* PsB = (bf16*)smem;                                 // aliases Qs after prologue
  bf16 (*Ks)[8][64][8] = (bf16(*)[8][64][8])(smem + 16384); // [2][8][64][8] 16KB
  bf16 (*Vs)[64][8] = (bf16(*)[64][8])(smem + 32768);       // [8][64][8] 8KB (single)

  int t = threadIdx.x, w = t >> 6, lane = t & 63;
  int q15 = lane & 15, quad = lane >> 4;
  int lid = blockIdx.x + (blockIdx.y << 3);
  int xcd = lid & 7, rr = lid >> 3;
  int q0 = (rr & 7) * 128;
  int bh = xcd + ((rr >> 3) << 3);
  int b = bh >> 4, h = bh & 15;

  const bf16* Qg = qkvb + (size_t)(b * 1024 + q0) * 3072 + h * 64;
  const bf16* Kg = qkvb + (size_t)(b * 1024) * 3072 + 1024 + h * 64;
  const bf16* Vg = Vt + (size_t)(bh * 64) * 1024;

  // prologue: stage Q tile + K tile 0 (buffer 0) + V tile 0
#pragma unroll
  for (int cc = 0; cc < 2; ++cc) {
    int kc = w * 2 + cc;
    async_load16(Qg + (size_t)lane * 3072 + kc * 8,        &Qs[kc][0][0]);
    async_load16(Qg + (size_t)(64 + lane) * 3072 + kc * 8, &Qs[kc][64][0]);
  }
  {
    const bf16* Kg2 = Kg + (size_t)lane * 3072;
    const bf16* Vg2 = Vg + (size_t)lane * 1024;
    async_load16(Kg2 + (w * 2) * 8,     &Ks[0][w * 2][0][0]);
    async_load16(Kg2 + (w * 2 + 1) * 8, &Ks[0][w * 2 + 1][0][0]);
    async_load16(Vg2 + (w * 2) * 8,     &Vs[w * 2][0][0]);
    async_load16(Vg2 + (w * 2 + 1) * 8, &Vs[w * 2 + 1][0][0]);
  }
  __syncthreads();   // drains ALL prologue loads (vmcnt0+lgkm0)

  // hoist Q fragments (invariant over kv loop)
  bf16x8 qfr[2][2];
#pragma unroll
  for (int ks = 0; ks < 2; ++ks)
#pragma unroll
    for (int nt = 0; nt < 2; ++nt)
      qfr[ks][nt] = *(const bf16x8*)&Qs[ks * 4 + quad][w * 32 + nt * 16 + q15][0];

  floatx4 oacc[4][2];
  float l_i[2] = {0.f, 0.f};
#pragma unroll
  for (int nt = 0; nt < 2; ++nt)
#pragma unroll
    for (int mt = 0; mt < 4; ++mt) oacc[mt][nt] = (floatx4){0.f, 0.f, 0.f, 0.f};

  for (int kt = 0; kt < 16; ++kt) {
    int cur = kt & 1;
    // top: K(kt) landed (V(kt+0..) in-flight pair preserved); fence LDS reuse
    asm volatile("s_waitcnt vmcnt(2) lgkmcnt(0)\n\ts_barrier" ::: "memory");
    if (kt + 1 < 16) {
      int kv0n = (kt + 1) * 64;
      const bf16* Kg3 = Kg + (size_t)(kv0n + lane) * 3072;
      async_load16(Kg3 + (w * 2) * 8,     &Ks[cur ^ 1][w * 2][0][0]);
      async_load16(Kg3 + (w * 2 + 1) * 8, &Ks[cur ^ 1][w * 2 + 1][0][0]);
    }

    // S^T = K Q^T
    floatx4 sacc[4][2];
#pragma unroll
    for (int mt = 0; mt < 4; ++mt)
#pragma unroll
      for (int nt = 0; nt < 2; ++nt) sacc[mt][nt] = (floatx4){0.f, 0.f, 0.f, 0.f};
#pragma unroll
    for (int ks = 0; ks < 2; ++ks) {
      bf16x8 kf[4];
#pragma unroll
      for (int mt = 0; mt < 4; ++mt)
        kf[mt] = *(const bf16x8*)&Ks[cur][ks * 4 + quad][mt * 16 + q15][0];
#pragma unroll
      for (int mt = 0; mt < 4; ++mt)
#pragma unroll
        for (int nt = 0; nt < 2; ++nt)
          sacc[mt][nt] = mfma16(kf[mt], qfr[ks][nt], sacc[mt][nt]);
    }

    // softmax numerator: p = exp2(s) (no max/rescale; logits bounded)
#pragma unroll
    for (int nt = 0; nt < 2; ++nt) {
      float rsum = 0.f;
#pragma unroll
      for (int mt = 0; mt < 4; ++mt)
#pragma unroll
        for (int r = 0; r < 4; ++r) {
          float p = fexp2(sacc[mt][nt][r]);
          sacc[mt][nt][r] = p;
          rsum += p;
        }
      rsum += __shfl_xor(rsum, 16);
      rsum += __shfl_xor(rsum, 32);
      l_i[nt] += rsum;
    }

    // P^T -> per-wave LDS region (B-frag layout), same-wave RAW via lgkmcnt
#pragma unroll
    for (int nt = 0; nt < 2; ++nt)
#pragma unroll
      for (int mt = 0; mt < 4; ++mt) {
        bf16x4 pk = {(__bf16)sacc[mt][nt][0], (__bf16)sacc[mt][nt][1],
                     (__bf16)sacc[mt][nt][2], (__bf16)sacc[mt][nt][3]};
        int kc = mt * 2 + (quad >> 1);
        *(bf16x4*)&PsB[(size_t)(w * 2 + nt) * 1024 + kc * 128 + q15 * 8 + (quad & 1) * 4] = pk;
      }

    // mid: V(kt) landed across all waves (K(kt+1)'s 2 stay in flight)
    if (kt + 1 < 16)
      asm volatile("s_waitcnt vmcnt(2)\n\ts_barrier" ::: "memory");
    else
      asm volatile("s_waitcnt vmcnt(0)\n\ts_barrier" ::: "memory");

    // O^T += V^T P^T
#pragma unroll
    for (int ks = 0; ks < 2; ++ks) {
      bf16x8 vf[4], pf[2];
#pragma unroll
      for (int mt = 0; mt < 4; ++mt)
        vf[mt] = *(const bf16x8*)&Vs[ks * 4 + quad][mt * 16 + q15][0];
#pragma unroll
      for (int nt = 0; nt < 2; ++nt)
        pf[nt] = *(const bf16x8*)&PsB[(size_t)(w * 2 + nt) * 1024 + (ks * 4 + quad) * 128 + q15 * 8];
#pragma unroll
      for (int mt = 0; mt < 4; ++mt)
#pragma unroll
        for (int nt = 0; nt < 2; ++nt) oacc[mt][nt] = mfma16(vf[mt], pf[nt], oacc[mt][nt]);
    }

    // post-PV: all waves done reading Vs -> stage V(kt+1) over it
    if (kt + 1 < 16) {
      asm volatile("s_waitcnt lgkmcnt(0)\n\ts_barrier" ::: "memory");
      int kv0n = (kt + 1) * 64;
      const bf16* Vg3 = Vg + (size_t)lane * 1024 + kv0n;
      async_load16(Vg3 + (w * 2) * 8,     &Vs[w * 2][0][0]);
      async_load16(Vg3 + (w * 2 + 1) * 8, &Vs[w * 2 + 1][0][0]);
    }
  }

  __syncthreads();
  bf16* T = (bf16*)smem + w * 2304;   // [32 q][72]; overlaps dead Qs/PsB + Ks head
#pragma unroll
  for (int nt = 0; nt < 2; ++nt) {
    float inv = 1.f / l_i[nt];
#pragma unroll
    for (int mt = 0; mt < 4; ++mt) {
      bf16x4 pk = {(__bf16)(oacc[mt][nt][0] * inv), (__bf16)(oacc[mt][nt][1] * inv),
                   (__bf16)(oacc[mt][nt][2] * inv), (__bf16)(oacc[mt][nt][3] * inv)};
      *(bf16x4*)&T[(nt * 16 + q15) * 72 + mt * 16 + quad * 4] = pk;
    }
  }
  __syncthreads();
  int row = lane >> 1, ch = (lane & 1) * 32;
  const bf16* Tr = T + row * 72 + ch;
  bf16* outp = attn_out + (size_t)(b * 1024 + q0 + w * 32 + row) * 1024 + h * 64 + ch;
#pragma unroll
  for (int i = 0; i < 4; ++i) *(bf16x8*)&outp[i * 8] = *(const bf16x8*)&Tr[i * 8];
}

// ---------------------------------------------------------------------------
extern "C" void kernel_launch(void* const* d_in, const int* in_sizes, int n_in,
                              void* d_out, int out_size, void* d_ws, size_t ws_size,
                              hipStream_t stream) {
  (void)in_sizes; (void)n_in; (void)out_size; (void)ws_size;
  const float* x       = (const float*)d_in[0];   // 8x1024x1024
  const float* W_qkv   = (const float*)d_in[1];   // 3072x1024
  const float* W_proj  = (const float*)d_in[2];   // 1024x1024
  const float* b_proj  = (const float*)d_in[3];   // 1024
  const float* coef_k  = (const float*)d_in[4];   // 10x3000
  const float* coef_v  = (const float*)d_in[5];   // 10x3000
  const int*   indices = (const int*)d_in[6];     // 10x3000
  const int*   task    = (const int*)d_in[7];     // scalar

  // Workspace (106 MB peak). attn_out aliases the dead Sf/S2b/Tt region.
  char* w8 = (char*)d_ws;
  float* Sf     = (float*)(w8);                   // 8MB  (2 fp32 planes, transient)
  bf16*  S2b    = (bf16*) (w8 + (8u  << 20));     // 4MB  [2048][1024] (transient)
  bf16*  Tt     = (bf16*) (w8 + (12u << 20));     // 4MB  [2][1024][1024] (transient)
  bf16*  Bmtb   = (bf16*) (w8 + (16u << 20));     // 2MB
  bf16*  Wcb    = (bf16*) (w8 + (18u << 20));     // 6MB  [3072][1024]
  bf16*  xb     = (bf16*) (w8 + (24u << 20));     // 16MB
  bf16*  qkvb   = (bf16*) (w8 + (40u << 20));     // 48MB [8192][3072]
  bf16*  Vt     = (bf16*) (w8 + (88u << 20));     // 16MB [128][64][1024]
  bf16*  Wprojb = (bf16*) (w8 + (104u << 20));    // 2MB
  bf16*  attnout= (bf16*) (w8);                   // 16MB alias (Sf/S2b/Tt dead)

  // Dense S scatter (fp32 planes), then ONE merged prep launch
  hipMemsetAsync(Sf, 0, (size_t)8 << 20, stream);
  scatter_s<<<118, 256, 0, stream>>>(coef_k, coef_v, indices, task, Sf);
  prep_kernel<<<13312, 256, 0, stream>>>(W_qkv, W_proj, x, Sf,
                                         Bmtb, Wcb, Wprojb, xb, S2b);

  // LoRA: T = S @ Bm (stored transposed per plane), then both band GEMMs
  gemm64_bf16_nt<<<dim3(16, 32), 256, 0, stream>>>(S2b, Bmtb, nullptr, nullptr,
                                                   nullptr, nullptr, Tt, 0, 1024);
  gemm64_bf16_nt<<<dim3(16, 16, 2), 256, 0, stream>>>(Bmtb, Tt, Wcb + (1u << 20), nullptr,
                                                      W_qkv + (1u << 20), nullptr, nullptr,
                                                      1 << 30, 1024);

  // qkv = xb @ Wcb^T -> q,k bands bf16 into qkvb; v band transposed into Vt.
  gemm256_qkv<<<dim3(12, 32), 512, 0, stream>>>(xb, Wcb, qkvb, Vt);

  // attention (R13: 40KB LDS -> 4 blocks/CU)
  attn_mfma<<<dim3(8, 128), 256, 0, stream>>>(qkvb, Vt, attnout);

  // out = attn_out @ W_proj^T + b_proj  (fp32 out)
  // R13: 256x128-tile one-round kernel (256 blocks = 1/CU exactly).
  gemm256_proj<<<dim3(8, 32), 512, 0, stream>>>(attnout, Wprojb, (float*)d_out, b_proj);
}